// Round 1
// baseline (617.353 us; speedup 1.0000x reference)
//
#include <hip/hip_runtime.h>
#include <hip/hip_bf16.h>
#include <math.h>

#define GN 19            // graph nodes
#define BB 256
#define TT 256

typedef short short8 __attribute__((ext_vector_type(8)));
typedef float f4 __attribute__((ext_vector_type(4)));

union Frag { int i[4]; short8 s; };

// wave-local LDS ordering fence: wait LDS ops, NO vmcnt drain, no barrier.
#define LWAIT() __asm__ volatile("s_waitcnt lgkmcnt(0)" ::: "memory")
// workgroup barrier WITHOUT vmcnt(0) drain: global loads/stores stay in flight.
#define WGBAR() __asm__ volatile("s_waitcnt lgkmcnt(0)\ns_barrier" ::: "memory")

// packed RNE float pair -> bf16 pair (v_cvt_pk_bf16_f32 on gfx950)
__device__ __forceinline__ int pkbf(float a, float b) {
    __hip_bfloat162 h2 = __float22bfloat162_rn(make_float2(a, b));
    union { __hip_bfloat162 h; int i; } u; u.h = h2; return u.i;
}

__device__ __forceinline__ float rl(float v, int j) {
    return __int_as_float(__builtin_amdgcn_readlane(__float_as_int(v), j));
}
__device__ __forceinline__ float fexp2(float x) { return __builtin_amdgcn_exp2f(x); }
__device__ __forceinline__ float frcp(float x)  { return __builtin_amdgcn_rcpf(x); }
__device__ __forceinline__ float sigm(float x)  { return frcp(1.f + fexp2(-1.4426950408889634f * x)); }
__device__ __forceinline__ float tanha(float x) { float e = fexp2(2.8853900817779268f * x); return 1.f - 2.f * frcp(e + 1.f); }

// ---------------------------------------------------------------------------
// Kernel A: graph encoder via bf16 MFMA (16x16x32).  One wave per block,
// grid-stride over graphs.  1-wave workgroup => no s_barrier needed at all;
// phase ordering via lgkmcnt waits only (global loads stay in flight).
// Next graph's A is register-prefetched during the current graph's pipeline.
// ---------------------------------------------------------------------------
__global__ __launch_bounds__(64) void encoder_mfma(
    const float* __restrict__ conn,   // (G,19,19)
    const int*   __restrict__ mask,   // (G)
    const float* __restrict__ w1_w,   // (64,19)
    const float* __restrict__ w1_b,   // (64)
    const float* __restrict__ w2_w,   // (64,64)
    const float* __restrict__ w2_b,   // (64)
    float* __restrict__ emb,          // (G,64)
    int num_graphs)
{
    __shared__ float S[2304];         // 9216 B, reused 4 ways
    __shared__ float dis[32];
    __shared__ float ps[256];

    const int t = threadIdx.x;
    const int l15 = t & 15;
    const int quad = t >> 4;

    // k-validity mask for B-operand repacks (k = quad*8+j < 19)
    float km[8];
    #pragma unroll
    for (int j = 0; j < 8; ++j) km[j] = (quad * 8 + j < GN) ? 1.f : 0.f;

    // loop-invariant scatter coords for A staging (e = t + 64*i)
    int rr[6], cc[6];
    #pragma unroll
    for (int i = 0; i < 6; ++i) {
        int e = t + 64 * i;
        rr[i] = e / GN;
        cc[i] = e - rr[i] * GN;
    }

    // ---- weight fragments + biases (once per block) ----
    Frag w1F[4];
    #pragma unroll
    for (int nt = 0; nt < 4; ++nt) {
        int n = nt * 16 + l15;
        #pragma unroll
        for (int p = 0; p < 4; ++p) {
            int k0 = quad * 8 + 2 * p, k1 = k0 + 1;
            float a = (k0 < GN) ? w1_w[n * GN + k0] : 0.f;
            float b = (k1 < GN) ? w1_w[n * GN + k1] : 0.f;
            w1F[nt].i[p] = pkbf(a, b);
        }
    }
    Frag w2F[2][4];
    #pragma unroll
    for (int kt = 0; kt < 2; ++kt)
        #pragma unroll
        for (int nt = 0; nt < 4; ++nt) {
            int n = nt * 16 + l15;
            #pragma unroll
            for (int p = 0; p < 4; ++p) {
                int k = kt * 32 + quad * 8 + 2 * p;
                w2F[kt][nt].i[p] = pkbf(w2_w[n * 64 + k], w2_w[n * 64 + k + 1]);
            }
        }
    float b1v[4], b2v[4];
    #pragma unroll
    for (int nt = 0; nt < 4; ++nt) {
        b1v[nt] = w1_b[nt * 16 + l15];
        b2v[nt] = w2_b[nt * 16 + l15];
    }

    // prologue: prefetch first graph's A into registers
    float pf[6];
    {
        int g0 = blockIdx.x < num_graphs ? blockIdx.x : 0;
        const float* Ag = conn + (size_t)g0 * (GN * GN);
        #pragma unroll
        for (int i = 0; i < 6; ++i) {
            int e = t + 64 * i;
            if (e < GN * GN) pf[i] = Ag[e];
        }
    }

    #pragma unroll 1
    for (int g = blockIdx.x; g < num_graphs; g += gridDim.x) {
        // zero A region: rows 0..31, cols 0..31 (stride 68)
        #pragma unroll
        for (int i = 0; i < 4; ++i) {
            int s = t + 64 * i;          // 256 float4 slots
            int row = s >> 3, c4 = s & 7;
            f4 z = {0.f, 0.f, 0.f, 0.f};
            *(f4*)&S[row * 68 + c4 * 4] = z;
        }
        LWAIT();   // zeros before scatter (same addresses)
        // scatter prefetched A (361 floats)
        #pragma unroll
        for (int i = 0; i < 6; ++i) {
            if (t + 64 * i < GN * GN) S[rr[i] * 68 + cc[i]] = pf[i];
        }
        // issue prefetch for the NEXT graph (stays in flight all pipeline)
        {
            int gn = g + gridDim.x;
            const float* Ag = conn + (size_t)(gn < num_graphs ? gn : g) * (GN * GN);
            #pragma unroll
            for (int i = 0; i < 6; ++i) {
                int e = t + 64 * i;
                if (e < GN * GN) pf[i] = Ag[e];
            }
        }
        LWAIT();   // staging visible

        // degree -> dis (lanes 0..18), zero pad 19..31
        if (t < 32) {
            float dv = 0.f;
            if (t < GN) {
                float d = 1.0f;   // self loop
                #pragma unroll
                for (int c4 = 0; c4 < 8; ++c4) {
                    f4 v = *(f4*)&S[t * 68 + c4 * 4];
                    d += v.x + v.y + v.z + v.w;
                }
                dv = rsqrtf(d);
            }
            dis[t] = dv;
        }
        LWAIT();

        // pack aF (raw A) and anF (normalized adjacency), 2 M-tiles
        float dk[8];
        {
            f4 v0 = *(f4*)&dis[quad * 8];
            f4 v1 = *(f4*)&dis[quad * 8 + 4];
            dk[0]=v0.x; dk[1]=v0.y; dk[2]=v0.z; dk[3]=v0.w;
            dk[4]=v1.x; dk[5]=v1.y; dk[6]=v1.z; dk[7]=v1.w;
        }
        Frag aF[2], anF[2];
        #pragma unroll
        for (int mt = 0; mt < 2; ++mt) {
            int m = l15 + 16 * mt;
            float dm = dis[m];
            f4 v0 = *(f4*)&S[m * 68 + quad * 8];
            f4 v1 = *(f4*)&S[m * 68 + quad * 8 + 4];
            float av[8] = {v0.x, v0.y, v0.z, v0.w, v1.x, v1.y, v1.z, v1.w};
            float an[8];
            #pragma unroll
            for (int j = 0; j < 8; ++j) {
                int k = quad * 8 + j;
                an[j] = (av[j] + (m == k ? 1.f : 0.f)) * dm * dk[j];
            }
            #pragma unroll
            for (int p = 0; p < 4; ++p) {
                aF[mt].i[p]  = pkbf(av[2*p], av[2*p+1]);
                anF[mt].i[p] = pkbf(an[2*p], an[2*p+1]);
            }
        }
        LWAIT();   // A reads done before H1^T overwrites S

        // MFMA1: H1 = A @ W1^T + b1  -> S transposed (S[n*36 + k])
        #pragma unroll
        for (int mt = 0; mt < 2; ++mt)
            #pragma unroll
            for (int nt = 0; nt < 4; ++nt) {
                float bb = b1v[nt];
                f4 c = {bb, bb, bb, bb};
                c = __builtin_amdgcn_mfma_f32_16x16x32_bf16(aF[mt].s, w1F[nt].s, c, 0, 0, 0);
                int col = nt * 16 + l15;
                #pragma unroll
                for (int r = 0; r < 4; ++r)
                    S[col * 36 + (mt * 16 + quad * 4 + r)] = c[r];
            }
        LWAIT();

        // pack H1 as B-op: 2 x b128 per n-tile, mask k>=19
        Frag hF[4];
        #pragma unroll
        for (int nt = 0; nt < 4; ++nt) {
            int n = nt * 16 + l15;
            f4 v0 = *(f4*)&S[n * 36 + quad * 8];
            f4 v1 = *(f4*)&S[n * 36 + quad * 8 + 4];
            float vv[8] = {v0.x, v0.y, v0.z, v0.w, v1.x, v1.y, v1.z, v1.w};
            #pragma unroll
            for (int p = 0; p < 4; ++p)
                hF[nt].i[p] = pkbf(vv[2*p] * km[2*p], vv[2*p+1] * km[2*p+1]);
        }
        LWAIT();   // H1^T reads done

        // MFMA2: X1 = relu(An @ H1) -> S row-major (rows>=19 naturally zero)
        #pragma unroll
        for (int mt = 0; mt < 2; ++mt)
            #pragma unroll
            for (int nt = 0; nt < 4; ++nt) {
                f4 c = {0.f, 0.f, 0.f, 0.f};
                c = __builtin_amdgcn_mfma_f32_16x16x32_bf16(anF[mt].s, hF[nt].s, c, 0, 0, 0);
                int col = nt * 16 + l15;
                #pragma unroll
                for (int r = 0; r < 4; ++r)
                    S[(mt * 16 + quad * 4 + r) * 68 + col] = fmaxf(c[r], 0.f);
            }
        LWAIT();

        // pack X1 as A-op (2 b128 per (mt,kt))
        Frag xF[2][2];
        #pragma unroll
        for (int mt = 0; mt < 2; ++mt) {
            int m = l15 + 16 * mt;
            #pragma unroll
            for (int kt = 0; kt < 2; ++kt) {
                f4 v0 = *(f4*)&S[m * 68 + kt * 32 + quad * 8];
                f4 v1 = *(f4*)&S[m * 68 + kt * 32 + quad * 8 + 4];
                xF[mt][kt].i[0] = pkbf(v0.x, v0.y);
                xF[mt][kt].i[1] = pkbf(v0.z, v0.w);
                xF[mt][kt].i[2] = pkbf(v1.x, v1.y);
                xF[mt][kt].i[3] = pkbf(v1.z, v1.w);
            }
        }
        LWAIT();   // X1 reads done

        // MFMA3: H2 = X1 @ W2^T + b2 -> S transposed
        #pragma unroll
        for (int mt = 0; mt < 2; ++mt)
            #pragma unroll
            for (int nt = 0; nt < 4; ++nt) {
                float bb = b2v[nt];
                f4 c = {bb, bb, bb, bb};
                c = __builtin_amdgcn_mfma_f32_16x16x32_bf16(xF[mt][0].s, w2F[0][nt].s, c, 0, 0, 0);
                c = __builtin_amdgcn_mfma_f32_16x16x32_bf16(xF[mt][1].s, w2F[1][nt].s, c, 0, 0, 0);
                int col = nt * 16 + l15;
                #pragma unroll
                for (int r = 0; r < 4; ++r)
                    S[col * 36 + (mt * 16 + quad * 4 + r)] = c[r];
            }
        LWAIT();

        // pack H2 as B-op
        #pragma unroll
        for (int nt = 0; nt < 4; ++nt) {
            int n = nt * 16 + l15;
            f4 v0 = *(f4*)&S[n * 36 + quad * 8];
            f4 v1 = *(f4*)&S[n * 36 + quad * 8 + 4];
            float vv[8] = {v0.x, v0.y, v0.z, v0.w, v1.x, v1.y, v1.z, v1.w};
            #pragma unroll
            for (int p = 0; p < 4; ++p)
                hF[nt].i[p] = pkbf(vv[2*p] * km[2*p], vv[2*p+1] * km[2*p+1]);
        }

        // MFMA4: X2 = relu(An @ H2); column sums -> emb mean
        float cs[4];
        #pragma unroll
        for (int nt = 0; nt < 4; ++nt) cs[nt] = 0.f;
        #pragma unroll
        for (int mt = 0; mt < 2; ++mt)
            #pragma unroll
            for (int nt = 0; nt < 4; ++nt) {
                f4 c = {0.f, 0.f, 0.f, 0.f};
                c = __builtin_amdgcn_mfma_f32_16x16x32_bf16(anF[mt].s, hF[nt].s, c, 0, 0, 0);
                if (mt == 0) {
                    cs[nt] += fmaxf(c[0], 0.f) + fmaxf(c[1], 0.f)
                            + fmaxf(c[2], 0.f) + fmaxf(c[3], 0.f);
                } else if (quad == 0) {   // rows 16,17,18 valid
                    cs[nt] += fmaxf(c[0], 0.f) + fmaxf(c[1], 0.f) + fmaxf(c[2], 0.f);
                }
            }
        #pragma unroll
        for (int nt = 0; nt < 4; ++nt)
            ps[quad * 64 + nt * 16 + l15] = cs[nt];
        LWAIT();
        float tot = ps[t] + ps[64 + t] + ps[128 + t] + ps[192 + t];
        float mf = (float)mask[g];
        emb[(size_t)g * 64 + t] = tot * (1.f / 19.f) * mf;
        LWAIT();   // ps reads done before next iteration reuses LDS
    }
}

// ---------------------------------------------------------------------------
// Kernel B: BOTH LSTM layers + FC head, fused.  One block (8 waves) per batch
// element: waves 0-3 run layer 0 (exactly the old lstm_l0 dataflow), waves
// 4-7 run layer 1 lagged by TWO steps, consuming h0 through a double-buffered
// LDS slot.  The 2-step lag means every h0buf hand-off is separated from its
// consumer by an intervening per-step barrier, so the schedule keeps exactly
// ONE s_barrier per iteration (no vmcnt drain; x-row loads stay in flight).
// Two independent recurrent chains per SIMD hide each other's latency.
// h0seq never touches HBM; layer-1 output exists only as last_h -> head.
// ---------------------------------------------------------------------------
__global__ __launch_bounds__(512, 2) void lstm_fused(
    const float* __restrict__ x,      // (B*T, 64) = emb
    const int*   __restrict__ mask,   // (B, T)
    const float* __restrict__ Wih0, const float* __restrict__ Whh0,
    const float* __restrict__ bih0, const float* __restrict__ bhh0,
    const float* __restrict__ Wih1, const float* __restrict__ Whh1,
    const float* __restrict__ bih1, const float* __restrict__ bhh1,
    const float* __restrict__ fc1_w, const float* __restrict__ fc1_b,
    const float* __restrict__ fc2_w, const float* __restrict__ fc2_b,
    float* __restrict__ out)          // (B, 2)
{
    __shared__ float gs0[2][256];     // layer-0 gate exchange (dbuf)
    __shared__ float gs1[2][256];     // layer-1 gate exchange (dbuf)
    __shared__ float h0buf[2][64];    // layer-0 -> layer-1 hand-off (dbuf)
    __shared__ float hd[32];
    __shared__ int li_s;

    const int tid = threadIdx.x;      // 0..511
    const int grp = tid >> 8;         // 0: layer 0 (waves 0-3), 1: layer 1
    const int r   = tid & 255;        // gate row within the layer
    const int l   = tid & 63;
    const int b   = blockIdx.x;

    // per-layer weight rows (row r of Wih/Whh), bias
    const float* __restrict__ Wih = grp ? Wih1 : Wih0;
    const float* __restrict__ Whh = grp ? Whh1 : Whh0;
    float wi[64], wh[64];
    {
        const float4* p = (const float4*)(Wih + r * 64);
        const float4* q = (const float4*)(Whh + r * 64);
        #pragma unroll
        for (int j = 0; j < 16; ++j) {
            ((float4*)wi)[j] = p[j];
            ((float4*)wh)[j] = q[j];
        }
    }
    const float bias = grp ? (bih1[r] + bhh1[r]) : (bih0[r] + bhh0[r]);

    // last_idx = clip(sum(mask)-1, 0, T-1)
    if (tid < 256) gs0[0][tid] = (float)mask[b * TT + tid];
    __syncthreads();
    if (tid == 0) {
        float s = 0.f;
        for (int t = 0; t < TT; ++t) s += gs0[0][t];
        int li = (int)s - 1;
        li = li < 0 ? 0 : (li > TT - 1 ? TT - 1 : li);
        li_s = li;
    }
    __syncthreads();
    const int lastidx = li_s;

    const float* __restrict__ xb = x + (size_t)b * TT * 64;
    float (*gsL)[256] = grp ? gs1 : gs0;

    float h = 0.f, c = 0.f, xc = 0.f, hl = 0.f;

    // layer-0 prologue: x-contribution for t = 0
    if (grp == 0) {
        float n0 = 0.f, n1 = 0.f, n2 = 0.f, n3 = 0.f;
        #pragma unroll
        for (int j = 0; j < 64; j += 4) {
            n0 = fmaf(xb[j],     wi[j],     n0);
            n1 = fmaf(xb[j + 1], wi[j + 1], n1);
            n2 = fmaf(xb[j + 2], wi[j + 2], n2);
            n3 = fmaf(xb[j + 3], wi[j + 3], n3);
        }
        xc = (n0 + n1) + (n2 + n3);
    }

    // iteration it: layer 0 processes step it; layer 1 processes step it-2.
    #pragma unroll 1
    for (int it = 0; it < TT + 2; ++it) {
        const int p = it & 1;

        // ---------------- phase A: gate compute ----------------
        f4 xr[16];
        if (grp == 0) {
            // issue raw loads of x row (it+1) NOW (consumed in phase B)
            int tn = it + 1; if (tn > TT - 1) tn = TT - 1;
            const f4* __restrict__ ern = (const f4*)(xb + (size_t)tn * 64);
            #pragma unroll
            for (int k = 0; k < 16; ++k) xr[k] = ern[k];

            if (it < TT) {
                // gates0(it) = bias + xc(it) + Whh0 . h0(it-1)
                float a0 = bias + xc, a1 = 0.f, a2 = 0.f, a3 = 0.f;
                #pragma unroll
                for (int j = 0; j < 64; j += 4) {
                    a0 = fmaf(rl(h, j),     wh[j],     a0);
                    a1 = fmaf(rl(h, j + 1), wh[j + 1], a1);
                    a2 = fmaf(rl(h, j + 2), wh[j + 2], a2);
                    a3 = fmaf(rl(h, j + 3), wh[j + 3], a3);
                }
                gs0[p][r] = (a0 + a1) + (a2 + a3);
            }
        } else {
            if (it >= 2) {
                // gates1(it-2) = bias + x1c(it-2) + Whh1 . h1(it-3)
                float a0 = bias + xc, a1 = 0.f, a2 = 0.f, a3 = 0.f;
                #pragma unroll
                for (int j = 0; j < 64; j += 4) {
                    a0 = fmaf(rl(h, j),     wh[j],     a0);
                    a1 = fmaf(rl(h, j + 1), wh[j + 1], a1);
                    a2 = fmaf(rl(h, j + 2), wh[j + 2], a2);
                    a3 = fmaf(rl(h, j + 3), wh[j + 3], a3);
                }
                gs1[p][r] = (a0 + a1) + (a2 + a3);
            }
        }

        WGBAR();   // lgkmcnt(0) + s_barrier, NO vmcnt drain

        // ---------------- phase B: activate + next x-contribution ----------
        if (grp == 0) {
            if (it < TT) {
                const float* gp = gs0[p];
                float gi = gp[l], gf = gp[64 + l], gg = gp[128 + l], go = gp[192 + l];
                c = sigm(gf) * c + sigm(gi) * tanha(gg);
                h = sigm(go) * tanha(c);
                if (tid < 64) h0buf[p][l] = h;   // wave 0 publishes h0(it)
            }
            // xc(it+1) from prefetched regs
            float n0 = 0.f, n1 = 0.f, n2 = 0.f, n3 = 0.f;
            #pragma unroll
            for (int k = 0; k < 16; ++k) {
                f4 v = xr[k];
                n0 = fmaf(v.x, wi[4*k],     n0);
                n1 = fmaf(v.y, wi[4*k + 1], n1);
                n2 = fmaf(v.z, wi[4*k + 2], n2);
                n3 = fmaf(v.w, wi[4*k + 3], n3);
            }
            xc = (n0 + n1) + (n2 + n3);
        } else {
            if (it >= 2) {
                const float* gp = gs1[p];
                float gi = gp[l], gf = gp[64 + l], gg = gp[128 + l], go = gp[192 + l];
                c = sigm(gf) * c + sigm(gi) * tanha(gg);
                h = sigm(go) * tanha(c);
                if (it - 2 == lastidx) hl = h;
            }
            // x1c(it-1) = Wih1 . h0(it-1); h0buf[p^1] was written at B(it-1)
            // and is separated from this read by BAR(it).
            if (it >= 1 && it <= TT) {
                const f4* __restrict__ hp = (const f4*)h0buf[p ^ 1];
                float n0 = 0.f, n1 = 0.f, n2 = 0.f, n3 = 0.f;
                #pragma unroll
                for (int k = 0; k < 16; ++k) {
                    f4 v = hp[k];
                    n0 = fmaf(v.x, wi[4*k],     n0);
                    n1 = fmaf(v.y, wi[4*k + 1], n1);
                    n2 = fmaf(v.z, wi[4*k + 2], n2);
                    n3 = fmaf(v.w, wi[4*k + 3], n3);
                }
                xc = (n0 + n1) + (n2 + n3);
            }
        }
    }

    // head: fc1 (64->32) relu, fc2 (32->2); wave 4 only (holds hl replicated)
    if (grp == 1 && r < 64) {
        if (l < 32) {
            float acc = fc1_b[l];
            const float* fw = fc1_w + l * 64;
            #pragma unroll
            for (int j = 0; j < 64; ++j)
                acc = fmaf(fw[j], rl(hl, j), acc);
            hd[l] = fmaxf(acc, 0.f);
        }
        LWAIT();   // same-wave LDS handoff
        if (l < 2) {
            float acc = fc2_b[l];
            #pragma unroll
            for (int j = 0; j < 32; ++j)
                acc = fmaf(fc2_w[l * 32 + j], hd[j], acc);
            out[b * 2 + l] = acc;
        }
    }
}

// ---------------------------------------------------------------------------
extern "C" void kernel_launch(void* const* d_in, const int* in_sizes, int n_in,
                              void* d_out, int out_size, void* d_ws, size_t ws_size,
                              hipStream_t stream)
{
    const float* conn  = (const float*)d_in[0];
    const int*   mask  = (const int*)  d_in[1];
    const float* w1_w  = (const float*)d_in[2];
    const float* w1_b  = (const float*)d_in[3];
    const float* w2_w  = (const float*)d_in[4];
    const float* w2_b  = (const float*)d_in[5];
    const float* Wih0  = (const float*)d_in[6];
    const float* Whh0  = (const float*)d_in[7];
    const float* bih0  = (const float*)d_in[8];
    const float* bhh0  = (const float*)d_in[9];
    const float* Wih1  = (const float*)d_in[10];
    const float* Whh1  = (const float*)d_in[11];
    const float* bih1  = (const float*)d_in[12];
    const float* bhh1  = (const float*)d_in[13];
    const float* fc1_w = (const float*)d_in[14];
    const float* fc1_b = (const float*)d_in[15];
    const float* fc2_w = (const float*)d_in[16];
    const float* fc2_b = (const float*)d_in[17];

    float* out = (float*)d_out;
    float* emb = (float*)d_ws;        // 16.8 MB (h0seq eliminated)

    const int num_graphs = BB * TT;

    encoder_mfma<<<8192, 64, 0, stream>>>(
        conn, mask, w1_w, w1_b, w2_w, w2_b, emb, num_graphs);

    lstm_fused<<<BB, 512, 0, stream>>>(
        emb, mask, Wih0, Whh0, bih0, bhh0, Wih1, Whh1, bih1, bhh1,
        fc1_w, fc1_b, fc2_w, fc2_b, out);
}

// Round 2
// 615.173 us; speedup vs baseline: 1.0035x; 1.0035x over previous
//
#include <hip/hip_runtime.h>
#include <hip/hip_bf16.h>
#include <math.h>

#define GN 19            // graph nodes
#define BB 256
#define TT 256

typedef short short8 __attribute__((ext_vector_type(8)));
typedef float f4 __attribute__((ext_vector_type(4)));

union Frag { int i[4]; short8 s; };

// wave-local LDS ordering fence: wait LDS ops, NO vmcnt drain, no barrier.
#define LWAIT() __asm__ volatile("s_waitcnt lgkmcnt(0)" ::: "memory")
// workgroup barrier WITHOUT vmcnt(0) drain: global loads stay in flight.
#define WGBAR() __asm__ volatile("s_waitcnt lgkmcnt(0)\ns_barrier" ::: "memory")

#define MFMA(a,b,c) __builtin_amdgcn_mfma_f32_16x16x32_bf16(a,b,c,0,0,0)

// packed RNE float pair -> bf16 pair (v_cvt_pk_bf16_f32 on gfx950)
__device__ __forceinline__ int pkbf(float a, float b) {
    __hip_bfloat162 h2 = __float22bfloat162_rn(make_float2(a, b));
    union { __hip_bfloat162 h; int i; } u; u.h = h2; return u.i;
}

__device__ __forceinline__ float fexp2(float x) { return __builtin_amdgcn_exp2f(x); }
__device__ __forceinline__ float frcp(float x)  { return __builtin_amdgcn_rcpf(x); }
__device__ __forceinline__ float sigm(float x)  { return frcp(1.f + fexp2(-1.4426950408889634f * x)); }
__device__ __forceinline__ float tanha(float x) { float e = fexp2(2.8853900817779268f * x); return 1.f - 2.f * frcp(e + 1.f); }

// ---------------------------------------------------------------------------
// Kernel A: graph encoder via bf16 MFMA (16x16x32).  UNCHANGED from R0.
// ---------------------------------------------------------------------------
__global__ __launch_bounds__(64) void encoder_mfma(
    const float* __restrict__ conn,   // (G,19,19)
    const int*   __restrict__ mask,   // (G)
    const float* __restrict__ w1_w,   // (64,19)
    const float* __restrict__ w1_b,   // (64)
    const float* __restrict__ w2_w,   // (64,64)
    const float* __restrict__ w2_b,   // (64)
    float* __restrict__ emb,          // (G,64)
    int num_graphs)
{
    __shared__ float S[2304];         // 9216 B, reused 4 ways
    __shared__ float dis[32];
    __shared__ float ps[256];

    const int t = threadIdx.x;
    const int l15 = t & 15;
    const int quad = t >> 4;

    float km[8];
    #pragma unroll
    for (int j = 0; j < 8; ++j) km[j] = (quad * 8 + j < GN) ? 1.f : 0.f;

    int rr[6], cc[6];
    #pragma unroll
    for (int i = 0; i < 6; ++i) {
        int e = t + 64 * i;
        rr[i] = e / GN;
        cc[i] = e - rr[i] * GN;
    }

    Frag w1F[4];
    #pragma unroll
    for (int nt = 0; nt < 4; ++nt) {
        int n = nt * 16 + l15;
        #pragma unroll
        for (int p = 0; p < 4; ++p) {
            int k0 = quad * 8 + 2 * p, k1 = k0 + 1;
            float a = (k0 < GN) ? w1_w[n * GN + k0] : 0.f;
            float b = (k1 < GN) ? w1_w[n * GN + k1] : 0.f;
            w1F[nt].i[p] = pkbf(a, b);
        }
    }
    Frag w2F[2][4];
    #pragma unroll
    for (int kt = 0; kt < 2; ++kt)
        #pragma unroll
        for (int nt = 0; nt < 4; ++nt) {
            int n = nt * 16 + l15;
            #pragma unroll
            for (int p = 0; p < 4; ++p) {
                int k = kt * 32 + quad * 8 + 2 * p;
                w2F[kt][nt].i[p] = pkbf(w2_w[n * 64 + k], w2_w[n * 64 + k + 1]);
            }
        }
    float b1v[4], b2v[4];
    #pragma unroll
    for (int nt = 0; nt < 4; ++nt) {
        b1v[nt] = w1_b[nt * 16 + l15];
        b2v[nt] = w2_b[nt * 16 + l15];
    }

    float pf[6];
    {
        int g0 = blockIdx.x < num_graphs ? blockIdx.x : 0;
        const float* Ag = conn + (size_t)g0 * (GN * GN);
        #pragma unroll
        for (int i = 0; i < 6; ++i) {
            int e = t + 64 * i;
            if (e < GN * GN) pf[i] = Ag[e];
        }
    }

    #pragma unroll 1
    for (int g = blockIdx.x; g < num_graphs; g += gridDim.x) {
        #pragma unroll
        for (int i = 0; i < 4; ++i) {
            int s = t + 64 * i;
            int row = s >> 3, c4 = s & 7;
            f4 z = {0.f, 0.f, 0.f, 0.f};
            *(f4*)&S[row * 68 + c4 * 4] = z;
        }
        LWAIT();
        #pragma unroll
        for (int i = 0; i < 6; ++i) {
            if (t + 64 * i < GN * GN) S[rr[i] * 68 + cc[i]] = pf[i];
        }
        {
            int gn = g + gridDim.x;
            const float* Ag = conn + (size_t)(gn < num_graphs ? gn : g) * (GN * GN);
            #pragma unroll
            for (int i = 0; i < 6; ++i) {
                int e = t + 64 * i;
                if (e < GN * GN) pf[i] = Ag[e];
            }
        }
        LWAIT();

        if (t < 32) {
            float dv = 0.f;
            if (t < GN) {
                float d = 1.0f;
                #pragma unroll
                for (int c4 = 0; c4 < 8; ++c4) {
                    f4 v = *(f4*)&S[t * 68 + c4 * 4];
                    d += v.x + v.y + v.z + v.w;
                }
                dv = rsqrtf(d);
            }
            dis[t] = dv;
        }
        LWAIT();

        float dk[8];
        {
            f4 v0 = *(f4*)&dis[quad * 8];
            f4 v1 = *(f4*)&dis[quad * 8 + 4];
            dk[0]=v0.x; dk[1]=v0.y; dk[2]=v0.z; dk[3]=v0.w;
            dk[4]=v1.x; dk[5]=v1.y; dk[6]=v1.z; dk[7]=v1.w;
        }
        Frag aF[2], anF[2];
        #pragma unroll
        for (int mt = 0; mt < 2; ++mt) {
            int m = l15 + 16 * mt;
            float dm = dis[m];
            f4 v0 = *(f4*)&S[m * 68 + quad * 8];
            f4 v1 = *(f4*)&S[m * 68 + quad * 8 + 4];
            float av[8] = {v0.x, v0.y, v0.z, v0.w, v1.x, v1.y, v1.z, v1.w};
            float an[8];
            #pragma unroll
            for (int j = 0; j < 8; ++j) {
                int k = quad * 8 + j;
                an[j] = (av[j] + (m == k ? 1.f : 0.f)) * dm * dk[j];
            }
            #pragma unroll
            for (int p = 0; p < 4; ++p) {
                aF[mt].i[p]  = pkbf(av[2*p], av[2*p+1]);
                anF[mt].i[p] = pkbf(an[2*p], an[2*p+1]);
            }
        }
        LWAIT();

        #pragma unroll
        for (int mt = 0; mt < 2; ++mt)
            #pragma unroll
            for (int nt = 0; nt < 4; ++nt) {
                float bb = b1v[nt];
                f4 c = {bb, bb, bb, bb};
                c = MFMA(aF[mt].s, w1F[nt].s, c);
                int col = nt * 16 + l15;
                #pragma unroll
                for (int r = 0; r < 4; ++r)
                    S[col * 36 + (mt * 16 + quad * 4 + r)] = c[r];
            }
        LWAIT();

        Frag hF[4];
        #pragma unroll
        for (int nt = 0; nt < 4; ++nt) {
            int n = nt * 16 + l15;
            f4 v0 = *(f4*)&S[n * 36 + quad * 8];
            f4 v1 = *(f4*)&S[n * 36 + quad * 8 + 4];
            float vv[8] = {v0.x, v0.y, v0.z, v0.w, v1.x, v1.y, v1.z, v1.w};
            #pragma unroll
            for (int p = 0; p < 4; ++p)
                hF[nt].i[p] = pkbf(vv[2*p] * km[2*p], vv[2*p+1] * km[2*p+1]);
        }
        LWAIT();

        #pragma unroll
        for (int mt = 0; mt < 2; ++mt)
            #pragma unroll
            for (int nt = 0; nt < 4; ++nt) {
                f4 c = {0.f, 0.f, 0.f, 0.f};
                c = MFMA(anF[mt].s, hF[nt].s, c);
                int col = nt * 16 + l15;
                #pragma unroll
                for (int r = 0; r < 4; ++r)
                    S[(mt * 16 + quad * 4 + r) * 68 + col] = fmaxf(c[r], 0.f);
            }
        LWAIT();

        Frag xF[2][2];
        #pragma unroll
        for (int mt = 0; mt < 2; ++mt) {
            int m = l15 + 16 * mt;
            #pragma unroll
            for (int kt = 0; kt < 2; ++kt) {
                f4 v0 = *(f4*)&S[m * 68 + kt * 32 + quad * 8];
                f4 v1 = *(f4*)&S[m * 68 + kt * 32 + quad * 8 + 4];
                xF[mt][kt].i[0] = pkbf(v0.x, v0.y);
                xF[mt][kt].i[1] = pkbf(v0.z, v0.w);
                xF[mt][kt].i[2] = pkbf(v1.x, v1.y);
                xF[mt][kt].i[3] = pkbf(v1.z, v1.w);
            }
        }
        LWAIT();

        #pragma unroll
        for (int mt = 0; mt < 2; ++mt)
            #pragma unroll
            for (int nt = 0; nt < 4; ++nt) {
                float bb = b2v[nt];
                f4 c = {bb, bb, bb, bb};
                c = MFMA(xF[mt][0].s, w2F[0][nt].s, c);
                c = MFMA(xF[mt][1].s, w2F[1][nt].s, c);
                int col = nt * 16 + l15;
                #pragma unroll
                for (int r = 0; r < 4; ++r)
                    S[col * 36 + (mt * 16 + quad * 4 + r)] = c[r];
            }
        LWAIT();

        Frag hG[4];
        #pragma unroll
        for (int nt = 0; nt < 4; ++nt) {
            int n = nt * 16 + l15;
            f4 v0 = *(f4*)&S[n * 36 + quad * 8];
            f4 v1 = *(f4*)&S[n * 36 + quad * 8 + 4];
            float vv[8] = {v0.x, v0.y, v0.z, v0.w, v1.x, v1.y, v1.z, v1.w};
            #pragma unroll
            for (int p = 0; p < 4; ++p)
                hG[nt].i[p] = pkbf(vv[2*p] * km[2*p], vv[2*p+1] * km[2*p+1]);
        }

        float cs[4];
        #pragma unroll
        for (int nt = 0; nt < 4; ++nt) cs[nt] = 0.f;
        #pragma unroll
        for (int mt = 0; mt < 2; ++mt)
            #pragma unroll
            for (int nt = 0; nt < 4; ++nt) {
                f4 c = {0.f, 0.f, 0.f, 0.f};
                c = MFMA(anF[mt].s, hG[nt].s, c);
                if (mt == 0) {
                    cs[nt] += fmaxf(c[0], 0.f) + fmaxf(c[1], 0.f)
                            + fmaxf(c[2], 0.f) + fmaxf(c[3], 0.f);
                } else if (quad == 0) {
                    cs[nt] += fmaxf(c[0], 0.f) + fmaxf(c[1], 0.f) + fmaxf(c[2], 0.f);
                }
            }
        #pragma unroll
        for (int nt = 0; nt < 4; ++nt)
            ps[quad * 64 + nt * 16 + l15] = cs[nt];
        LWAIT();
        float tot = ps[t] + ps[64 + t] + ps[128 + t] + ps[192 + t];
        float mf = (float)mask[g];
        emb[(size_t)g * 64 + t] = tot * (1.f / 19.f) * mf;
        LWAIT();
    }
}

// ---------------------------------------------------------------------------
// Kernel B: both LSTM layers + head via MFMA.
// 16 blocks x 512 threads; block owns 16 batch rows.  Per step:
//   gates^T[256 x 16b] = W[256 x 64] @ H^T[64 x 16b]  (16x16x32 bf16 MFMA)
// Gate rows permuted unit-major (tile m covers units 4m..4m+3, quad-row = the
// 4 gates of one unit) so each lane's C-frag f4 = (i,f,g,o) of ONE (unit,
// batch): the c/h update is lane-local, full utilization, no cross-lane ops.
// Wave w owns gate-tiles {2w,2w+1} per layer: A-frags = weights, 64 VGPR,
// loaded ONCE (this fixes R0's diagnosis: weights were never register-
// resident, every step re-streamed 512B/thread through L1/L2).
// h carried as (hi,lo) bf16 pair -> recurrent path effectively f32; weights
// single bf16 (same treatment the encoder already passes with).
// Layer 1 lagged 1 step; ONE barrier per step; h exchange = 16x64 LDS.
// ---------------------------------------------------------------------------
__global__ __launch_bounds__(512, 2) void lstm_mfma(
    const float* __restrict__ x,      // (B*T, 64) = emb
    const int*   __restrict__ mask,   // (B, T)
    const float* __restrict__ Wih0, const float* __restrict__ Whh0,
    const float* __restrict__ bih0, const float* __restrict__ bhh0,
    const float* __restrict__ Wih1, const float* __restrict__ Whh1,
    const float* __restrict__ bih1, const float* __restrict__ bhh1,
    const float* __restrict__ fc1_w, const float* __restrict__ fc1_b,
    const float* __restrict__ fc2_w, const float* __restrict__ fc2_b,
    float* __restrict__ out)          // (B, 2)
{
    __shared__ int   h0b[2][16 * 68]; // packed (hi|lo) bf16 h0, [b][u], dbuf
    __shared__ int   h1b[2][16 * 68];
    __shared__ float hlast[16][68];
    __shared__ float red[512];
    __shared__ int   li_s[16];

    const int tid  = threadIdx.x;     // 0..511
    const int w    = tid >> 6;        // wave 0..7
    const int lane = tid & 63;
    const int l15  = lane & 15;       // batch col
    const int quad = lane >> 4;
    const int bb0  = blockIdx.x * 16;

    // ---- lastidx per batch row ----
    {
        int b16 = tid >> 5, j = tid & 31;
        int s = 0;
        #pragma unroll
        for (int c8 = 0; c8 < 8; ++c8)
            s += mask[(bb0 + b16) * TT + j + 32 * c8];
        red[tid] = (float)s;
    }
    __syncthreads();
    if (tid < 16) {
        float s = 0.f;
        #pragma unroll
        for (int j = 0; j < 32; ++j) s += red[tid * 32 + j];
        int li = (int)s - 1;
        li_s[tid] = li < 0 ? 0 : (li > TT - 1 ? TT - 1 : li);
    }
    __syncthreads();
    const int li = li_s[l15];

    // ---- weight A-fragments (once). A[row=l15][k=quad*8+j] of gate-tile mg.
    // tile-row r maps to orig gate row (r&3)*64 + (mg*4 + (r>>2)).
    Frag Aih0[2][2], Ahh0[2][2], Aih1[2][2], Ahh1[2][2];
    f4 bias0v[2], bias1v[2];
    #pragma unroll
    for (int mt = 0; mt < 2; ++mt) {
        int mg = 2 * w + mt;
        int orig = (l15 & 3) * 64 + (mg * 4 + (l15 >> 2));
        #pragma unroll
        for (int kt = 0; kt < 2; ++kt)
            #pragma unroll
            for (int p = 0; p < 4; ++p) {
                int k = kt * 32 + quad * 8 + 2 * p;
                Aih0[mt][kt].i[p] = pkbf(Wih0[orig * 64 + k], Wih0[orig * 64 + k + 1]);
                Ahh0[mt][kt].i[p] = pkbf(Whh0[orig * 64 + k], Whh0[orig * 64 + k + 1]);
                Aih1[mt][kt].i[p] = pkbf(Wih1[orig * 64 + k], Wih1[orig * 64 + k + 1]);
                Ahh1[mt][kt].i[p] = pkbf(Whh1[orig * 64 + k], Whh1[orig * 64 + k + 1]);
            }
        int uu = mg * 4 + quad;       // C-frag: row quad*4+r -> gate r, unit uu
        #pragma unroll
        for (int r = 0; r < 4; ++r) {
            bias0v[mt][r] = bih0[r * 64 + uu] + bhh0[r * 64 + uu];
            bias1v[mt][r] = bih1[r * 64 + uu] + bhh1[r * 64 + uu];
        }
    }
    const int uoff0 = (2 * w + 0) * 4 + quad;
    const int uoff1 = (2 * w + 1) * 4 + quad;

    // ---- state ----
    Frag BX[2], BH0h[2], BH0l[2], BH1h[2], BH1l[2];
    #pragma unroll
    for (int kt = 0; kt < 2; ++kt)
        #pragma unroll
        for (int p = 0; p < 4; ++p) {
            BX[kt].i[p] = 0; BH0h[kt].i[p] = 0; BH0l[kt].i[p] = 0;
            BH1h[kt].i[p] = 0; BH1l[kt].i[p] = 0;
        }
    float c0s[2] = {0.f, 0.f}, c1s[2] = {0.f, 0.f}, h1last[2] = {0.f, 0.f};

    const float* __restrict__ xb = x + (size_t)(bb0 + l15) * TT * 64;
    f4 xpre[4];
    {
        const f4* p0 = (const f4*)(xb + quad * 8);
        const f4* p1 = (const f4*)(xb + 32 + quad * 8);
        xpre[0] = p0[0]; xpre[1] = p0[1];
        xpre[2] = p1[0]; xpre[3] = p1[1];
    }

    // iteration it: layer 0 does step it; layer 1 does step it-1.
    #pragma unroll 1
    for (int it = 0; it <= TT; ++it) {
        const int cur = it & 1;

        if (it < TT) {
            // pack X(it) B-frags from prefetch regs
            #pragma unroll
            for (int kt = 0; kt < 2; ++kt) {
                f4 v0 = xpre[kt * 2], v1 = xpre[kt * 2 + 1];
                BX[kt].i[0] = pkbf(v0.x, v0.y);
                BX[kt].i[1] = pkbf(v0.z, v0.w);
                BX[kt].i[2] = pkbf(v1.x, v1.y);
                BX[kt].i[3] = pkbf(v1.z, v1.w);
            }
            // issue X(it+1) prefetch (stays in flight across the step)
            int tn = it + 1 < TT ? it + 1 : TT - 1;
            const f4* p0 = (const f4*)(xb + (size_t)tn * 64 + quad * 8);
            const f4* p1 = (const f4*)(xb + (size_t)tn * 64 + 32 + quad * 8);
            xpre[0] = p0[0]; xpre[1] = p0[1];
            xpre[2] = p1[0]; xpre[3] = p1[1];
        }

        // ---- MFMAs (all B-frags are pre-barrier state: H0(it-1), H1(it-2))
        f4 g0[2], g1[2];
        if (it < TT) {
            #pragma unroll
            for (int mt = 0; mt < 2; ++mt) {
                f4 c = bias0v[mt];
                c = MFMA(Aih0[mt][0].s, BX[0].s,   c);
                c = MFMA(Aih0[mt][1].s, BX[1].s,   c);
                c = MFMA(Ahh0[mt][0].s, BH0h[0].s, c);
                c = MFMA(Ahh0[mt][1].s, BH0h[1].s, c);
                c = MFMA(Ahh0[mt][0].s, BH0l[0].s, c);
                c = MFMA(Ahh0[mt][1].s, BH0l[1].s, c);
                g0[mt] = c;
            }
        }
        if (it >= 1) {
            #pragma unroll
            for (int mt = 0; mt < 2; ++mt) {
                f4 c = bias1v[mt];
                c = MFMA(Aih1[mt][0].s, BH0h[0].s, c);
                c = MFMA(Aih1[mt][1].s, BH0h[1].s, c);
                c = MFMA(Aih1[mt][0].s, BH0l[0].s, c);
                c = MFMA(Aih1[mt][1].s, BH0l[1].s, c);
                c = MFMA(Ahh1[mt][0].s, BH1h[0].s, c);
                c = MFMA(Ahh1[mt][1].s, BH1h[1].s, c);
                c = MFMA(Ahh1[mt][0].s, BH1l[0].s, c);
                c = MFMA(Ahh1[mt][1].s, BH1l[1].s, c);
                g1[mt] = c;
            }
        }

        // ---- lane-local activate + update, write packed h to LDS ----
        if (it < TT) {
            #pragma unroll
            for (int mt = 0; mt < 2; ++mt) {
                f4 g = g0[mt];
                float si = sigm(g[0]), sf = sigm(g[1]);
                float tg = tanha(g[2]), so = sigm(g[3]);
                float cc = fmaf(sf, c0s[mt], si * tg);
                c0s[mt] = cc;
                float h = so * tanha(cc);
                unsigned hb = __float_as_uint(h);
                float hhi = __uint_as_float(hb & 0xFFFF0000u);
                float hlo = h - hhi;
                unsigned lopk = (unsigned)pkbf(hlo, hlo);
                int packed = (int)__builtin_amdgcn_perm(lopk, hb, 0x05040302u);
                h0b[cur][l15 * 68 + (mt ? uoff1 : uoff0)] = packed;
            }
        }
        if (it >= 1) {
            #pragma unroll
            for (int mt = 0; mt < 2; ++mt) {
                f4 g = g1[mt];
                float si = sigm(g[0]), sf = sigm(g[1]);
                float tg = tanha(g[2]), so = sigm(g[3]);
                float cc = fmaf(sf, c1s[mt], si * tg);
                c1s[mt] = cc;
                float h = so * tanha(cc);
                if (it - 1 == li) h1last[mt] = h;
                unsigned hb = __float_as_uint(h);
                float hhi = __uint_as_float(hb & 0xFFFF0000u);
                float hlo = h - hhi;
                unsigned lopk = (unsigned)pkbf(hlo, hlo);
                int packed = (int)__builtin_amdgcn_perm(lopk, hb, 0x05040302u);
                h1b[cur][l15 * 68 + (mt ? uoff1 : uoff0)] = packed;
            }
        }

        WGBAR();   // lgkmcnt(0)+s_barrier; X prefetch stays in flight

        // ---- unpack next-step B-frags: B[k][b]=H[b][k], lane=b=l15 ----
        if (it < TT) {
            #pragma unroll
            for (int kt = 0; kt < 2; ++kt) {
                const int4* pp = (const int4*)&h0b[cur][l15 * 68 + kt * 32 + quad * 8];
                int4 va = pp[0], vb = pp[1];
                BH0h[kt].i[0] = (int)__builtin_amdgcn_perm((unsigned)va.y, (unsigned)va.x, 0x05040100u);
                BH0h[kt].i[1] = (int)__builtin_amdgcn_perm((unsigned)va.w, (unsigned)va.z, 0x05040100u);
                BH0h[kt].i[2] = (int)__builtin_amdgcn_perm((unsigned)vb.y, (unsigned)vb.x, 0x05040100u);
                BH0h[kt].i[3] = (int)__builtin_amdgcn_perm((unsigned)vb.w, (unsigned)vb.z, 0x05040100u);
                BH0l[kt].i[0] = (int)__builtin_amdgcn_perm((unsigned)va.y, (unsigned)va.x, 0x07060302u);
                BH0l[kt].i[1] = (int)__builtin_amdgcn_perm((unsigned)va.w, (unsigned)va.z, 0x07060302u);
                BH0l[kt].i[2] = (int)__builtin_amdgcn_perm((unsigned)vb.y, (unsigned)vb.x, 0x07060302u);
                BH0l[kt].i[3] = (int)__builtin_amdgcn_perm((unsigned)vb.w, (unsigned)vb.z, 0x07060302u);
            }
            if (it >= 1) {
                #pragma unroll
                for (int kt = 0; kt < 2; ++kt) {
                    const int4* pp = (const int4*)&h1b[cur][l15 * 68 + kt * 32 + quad * 8];
                    int4 va = pp[0], vb = pp[1];
                    BH1h[kt].i[0] = (int)__builtin_amdgcn_perm((unsigned)va.y, (unsigned)va.x, 0x05040100u);
                    BH1h[kt].i[1] = (int)__builtin_amdgcn_perm((unsigned)va.w, (unsigned)va.z, 0x05040100u);
                    BH1h[kt].i[2] = (int)__builtin_amdgcn_perm((unsigned)vb.y, (unsigned)vb.x, 0x05040100u);
                    BH1h[kt].i[3] = (int)__builtin_amdgcn_perm((unsigned)vb.w, (unsigned)vb.z, 0x05040100u);
                    BH1l[kt].i[0] = (int)__builtin_amdgcn_perm((unsigned)va.y, (unsigned)va.x, 0x07060302u);
                    BH1l[kt].i[1] = (int)__builtin_amdgcn_perm((unsigned)va.w, (unsigned)va.z, 0x07060302u);
                    BH1l[kt].i[2] = (int)__builtin_amdgcn_perm((unsigned)vb.y, (unsigned)vb.x, 0x07060302u);
                    BH1l[kt].i[3] = (int)__builtin_amdgcn_perm((unsigned)vb.w, (unsigned)vb.z, 0x07060302u);
                }
            }
        }
    }

    // ---- head ----
    hlast[l15][uoff0] = h1last[0];
    hlast[l15][uoff1] = h1last[1];
    __syncthreads();
    {
        int b = tid >> 5, o = tid & 31;
        float acc = fc1_b[o];
        const float* fw = fc1_w + o * 64;
        #pragma unroll
        for (int j = 0; j < 64; ++j)
            acc = fmaf(hlast[b][j], fw[j], acc);
        red[b * 32 + o] = fmaxf(acc, 0.f);
    }
    __syncthreads();
    if (tid < 32) {
        int b = tid >> 1, o = tid & 1;
        float acc = fc2_b[o];
        #pragma unroll
        for (int j = 0; j < 32; ++j)
            acc = fmaf(fc2_w[o * 32 + j], red[b * 32 + j], acc);
        out[(bb0 + b) * 2 + o] = acc;
    }
}

// ---------------------------------------------------------------------------
extern "C" void kernel_launch(void* const* d_in, const int* in_sizes, int n_in,
                              void* d_out, int out_size, void* d_ws, size_t ws_size,
                              hipStream_t stream)
{
    const float* conn  = (const float*)d_in[0];
    const int*   mask  = (const int*)  d_in[1];
    const float* w1_w  = (const float*)d_in[2];
    const float* w1_b  = (const float*)d_in[3];
    const float* w2_w  = (const float*)d_in[4];
    const float* w2_b  = (const float*)d_in[5];
    const float* Wih0  = (const float*)d_in[6];
    const float* Whh0  = (const float*)d_in[7];
    const float* bih0  = (const float*)d_in[8];
    const float* bhh0  = (const float*)d_in[9];
    const float* Wih1  = (const float*)d_in[10];
    const float* Whh1  = (const float*)d_in[11];
    const float* bih1  = (const float*)d_in[12];
    const float* bhh1  = (const float*)d_in[13];
    const float* fc1_w = (const float*)d_in[14];
    const float* fc1_b = (const float*)d_in[15];
    const float* fc2_w = (const float*)d_in[16];
    const float* fc2_b = (const float*)d_in[17];

    float* out = (float*)d_out;
    float* emb = (float*)d_ws;        // 16.8 MB

    const int num_graphs = BB * TT;

    encoder_mfma<<<8192, 64, 0, stream>>>(
        conn, mask, w1_w, w1_b, w2_w, w2_b, emb, num_graphs);

    lstm_mfma<<<16, 512, 0, stream>>>(
        emb, mask, Wih0, Whh0, bih0, bhh0, Wih1, Whh1, bih1, bhh1,
        fc1_w, fc1_b, fc2_w, fc2_b, out);
}

// Round 3
// 603.786 us; speedup vs baseline: 1.0225x; 1.0189x over previous
//
#include <hip/hip_runtime.h>
#include <hip/hip_bf16.h>
#include <math.h>

#define GN 19            // graph nodes
#define BB 256
#define TT 256

typedef short short8 __attribute__((ext_vector_type(8)));
typedef float f4 __attribute__((ext_vector_type(4)));

union Frag { int i[4]; short8 s; };

// wave-local LDS ordering fence: wait LDS ops, NO vmcnt drain, no barrier.
#define LWAIT() __asm__ volatile("s_waitcnt lgkmcnt(0)" ::: "memory")
// workgroup barrier WITHOUT vmcnt(0) drain: global loads stay in flight.
#define WGBAR() __asm__ volatile("s_waitcnt lgkmcnt(0)\ns_barrier" ::: "memory")
// opaque-register pin: value becomes asm-defined -> compiler cannot
// rematerialize it by re-loading memory (forces register residency).
#define PIN8(x) __asm__ volatile("" : "+v"(x))
#define PINF(x) __asm__ volatile("" : "+v"(x))

#define MFMA(a,b,c) __builtin_amdgcn_mfma_f32_16x16x32_bf16(a,b,c,0,0,0)

// packed RNE float pair -> bf16 pair (v_cvt_pk_bf16_f32 on gfx950)
__device__ __forceinline__ int pkbf(float a, float b) {
    __hip_bfloat162 h2 = __float22bfloat162_rn(make_float2(a, b));
    union { __hip_bfloat162 h; int i; } u; u.h = h2; return u.i;
}

__device__ __forceinline__ float fexp2(float x) { return __builtin_amdgcn_exp2f(x); }
__device__ __forceinline__ float frcp(float x)  { return __builtin_amdgcn_rcpf(x); }
__device__ __forceinline__ float sigm(float x)  { return frcp(1.f + fexp2(-1.4426950408889634f * x)); }
__device__ __forceinline__ float tanha(float x) { float e = fexp2(2.8853900817779268f * x); return 1.f - 2.f * frcp(e + 1.f); }

// ---------------------------------------------------------------------------
// Kernel A: graph encoder via bf16 MFMA (16x16x32).  UNCHANGED.
// ---------------------------------------------------------------------------
__global__ __launch_bounds__(64) void encoder_mfma(
    const float* __restrict__ conn,   // (G,19,19)
    const int*   __restrict__ mask,   // (G)
    const float* __restrict__ w1_w,   // (64,19)
    const float* __restrict__ w1_b,   // (64)
    const float* __restrict__ w2_w,   // (64,64)
    const float* __restrict__ w2_b,   // (64)
    float* __restrict__ emb,          // (G,64)
    int num_graphs)
{
    __shared__ float S[2304];         // 9216 B, reused 4 ways
    __shared__ float dis[32];
    __shared__ float ps[256];

    const int t = threadIdx.x;
    const int l15 = t & 15;
    const int quad = t >> 4;

    float km[8];
    #pragma unroll
    for (int j = 0; j < 8; ++j) km[j] = (quad * 8 + j < GN) ? 1.f : 0.f;

    int rr[6], cc[6];
    #pragma unroll
    for (int i = 0; i < 6; ++i) {
        int e = t + 64 * i;
        rr[i] = e / GN;
        cc[i] = e - rr[i] * GN;
    }

    Frag w1F[4];
    #pragma unroll
    for (int nt = 0; nt < 4; ++nt) {
        int n = nt * 16 + l15;
        #pragma unroll
        for (int p = 0; p < 4; ++p) {
            int k0 = quad * 8 + 2 * p, k1 = k0 + 1;
            float a = (k0 < GN) ? w1_w[n * GN + k0] : 0.f;
            float b = (k1 < GN) ? w1_w[n * GN + k1] : 0.f;
            w1F[nt].i[p] = pkbf(a, b);
        }
    }
    Frag w2F[2][4];
    #pragma unroll
    for (int kt = 0; kt < 2; ++kt)
        #pragma unroll
        for (int nt = 0; nt < 4; ++nt) {
            int n = nt * 16 + l15;
            #pragma unroll
            for (int p = 0; p < 4; ++p) {
                int k = kt * 32 + quad * 8 + 2 * p;
                w2F[kt][nt].i[p] = pkbf(w2_w[n * 64 + k], w2_w[n * 64 + k + 1]);
            }
        }
    float b1v[4], b2v[4];
    #pragma unroll
    for (int nt = 0; nt < 4; ++nt) {
        b1v[nt] = w1_b[nt * 16 + l15];
        b2v[nt] = w2_b[nt * 16 + l15];
    }

    float pf[6];
    {
        int g0 = blockIdx.x < num_graphs ? blockIdx.x : 0;
        const float* Ag = conn + (size_t)g0 * (GN * GN);
        #pragma unroll
        for (int i = 0; i < 6; ++i) {
            int e = t + 64 * i;
            if (e < GN * GN) pf[i] = Ag[e];
        }
    }

    #pragma unroll 1
    for (int g = blockIdx.x; g < num_graphs; g += gridDim.x) {
        #pragma unroll
        for (int i = 0; i < 4; ++i) {
            int s = t + 64 * i;
            int row = s >> 3, c4 = s & 7;
            f4 z = {0.f, 0.f, 0.f, 0.f};
            *(f4*)&S[row * 68 + c4 * 4] = z;
        }
        LWAIT();
        #pragma unroll
        for (int i = 0; i < 6; ++i) {
            if (t + 64 * i < GN * GN) S[rr[i] * 68 + cc[i]] = pf[i];
        }
        {
            int gn = g + gridDim.x;
            const float* Ag = conn + (size_t)(gn < num_graphs ? gn : g) * (GN * GN);
            #pragma unroll
            for (int i = 0; i < 6; ++i) {
                int e = t + 64 * i;
                if (e < GN * GN) pf[i] = Ag[e];
            }
        }
        LWAIT();

        if (t < 32) {
            float dv = 0.f;
            if (t < GN) {
                float d = 1.0f;
                #pragma unroll
                for (int c4 = 0; c4 < 8; ++c4) {
                    f4 v = *(f4*)&S[t * 68 + c4 * 4];
                    d += v.x + v.y + v.z + v.w;
                }
                dv = rsqrtf(d);
            }
            dis[t] = dv;
        }
        LWAIT();

        float dk[8];
        {
            f4 v0 = *(f4*)&dis[quad * 8];
            f4 v1 = *(f4*)&dis[quad * 8 + 4];
            dk[0]=v0.x; dk[1]=v0.y; dk[2]=v0.z; dk[3]=v0.w;
            dk[4]=v1.x; dk[5]=v1.y; dk[6]=v1.z; dk[7]=v1.w;
        }
        Frag aF[2], anF[2];
        #pragma unroll
        for (int mt = 0; mt < 2; ++mt) {
            int m = l15 + 16 * mt;
            float dm = dis[m];
            f4 v0 = *(f4*)&S[m * 68 + quad * 8];
            f4 v1 = *(f4*)&S[m * 68 + quad * 8 + 4];
            float av[8] = {v0.x, v0.y, v0.z, v0.w, v1.x, v1.y, v1.z, v1.w};
            float an[8];
            #pragma unroll
            for (int j = 0; j < 8; ++j) {
                int k = quad * 8 + j;
                an[j] = (av[j] + (m == k ? 1.f : 0.f)) * dm * dk[j];
            }
            #pragma unroll
            for (int p = 0; p < 4; ++p) {
                aF[mt].i[p]  = pkbf(av[2*p], av[2*p+1]);
                anF[mt].i[p] = pkbf(an[2*p], an[2*p+1]);
            }
        }
        LWAIT();

        #pragma unroll
        for (int mt = 0; mt < 2; ++mt)
            #pragma unroll
            for (int nt = 0; nt < 4; ++nt) {
                float bb = b1v[nt];
                f4 c = {bb, bb, bb, bb};
                c = MFMA(aF[mt].s, w1F[nt].s, c);
                int col = nt * 16 + l15;
                #pragma unroll
                for (int r = 0; r < 4; ++r)
                    S[col * 36 + (mt * 16 + quad * 4 + r)] = c[r];
            }
        LWAIT();

        Frag hF[4];
        #pragma unroll
        for (int nt = 0; nt < 4; ++nt) {
            int n = nt * 16 + l15;
            f4 v0 = *(f4*)&S[n * 36 + quad * 8];
            f4 v1 = *(f4*)&S[n * 36 + quad * 8 + 4];
            float vv[8] = {v0.x, v0.y, v0.z, v0.w, v1.x, v1.y, v1.z, v1.w};
            #pragma unroll
            for (int p = 0; p < 4; ++p)
                hF[nt].i[p] = pkbf(vv[2*p] * km[2*p], vv[2*p+1] * km[2*p+1]);
        }
        LWAIT();

        #pragma unroll
        for (int mt = 0; mt < 2; ++mt)
            #pragma unroll
            for (int nt = 0; nt < 4; ++nt) {
                f4 c = {0.f, 0.f, 0.f, 0.f};
                c = MFMA(anF[mt].s, hF[nt].s, c);
                int col = nt * 16 + l15;
                #pragma unroll
                for (int r = 0; r < 4; ++r)
                    S[(mt * 16 + quad * 4 + r) * 68 + col] = fmaxf(c[r], 0.f);
            }
        LWAIT();

        Frag xF[2][2];
        #pragma unroll
        for (int mt = 0; mt < 2; ++mt) {
            int m = l15 + 16 * mt;
            #pragma unroll
            for (int kt = 0; kt < 2; ++kt) {
                f4 v0 = *(f4*)&S[m * 68 + kt * 32 + quad * 8];
                f4 v1 = *(f4*)&S[m * 68 + kt * 32 + quad * 8 + 4];
                xF[mt][kt].i[0] = pkbf(v0.x, v0.y);
                xF[mt][kt].i[1] = pkbf(v0.z, v0.w);
                xF[mt][kt].i[2] = pkbf(v1.x, v1.y);
                xF[mt][kt].i[3] = pkbf(v1.z, v1.w);
            }
        }
        LWAIT();

        #pragma unroll
        for (int mt = 0; mt < 2; ++mt)
            #pragma unroll
            for (int nt = 0; nt < 4; ++nt) {
                float bb = b2v[nt];
                f4 c = {bb, bb, bb, bb};
                c = MFMA(xF[mt][0].s, w2F[0][nt].s, c);
                c = MFMA(xF[mt][1].s, w2F[1][nt].s, c);
                int col = nt * 16 + l15;
                #pragma unroll
                for (int r = 0; r < 4; ++r)
                    S[col * 36 + (mt * 16 + quad * 4 + r)] = c[r];
            }
        LWAIT();

        Frag hG[4];
        #pragma unroll
        for (int nt = 0; nt < 4; ++nt) {
            int n = nt * 16 + l15;
            f4 v0 = *(f4*)&S[n * 36 + quad * 8];
            f4 v1 = *(f4*)&S[n * 36 + quad * 8 + 4];
            float vv[8] = {v0.x, v0.y, v0.z, v0.w, v1.x, v1.y, v1.z, v1.w};
            #pragma unroll
            for (int p = 0; p < 4; ++p)
                hG[nt].i[p] = pkbf(vv[2*p] * km[2*p], vv[2*p+1] * km[2*p+1]);
        }

        float cs[4];
        #pragma unroll
        for (int nt = 0; nt < 4; ++nt) cs[nt] = 0.f;
        #pragma unroll
        for (int mt = 0; mt < 2; ++mt)
            #pragma unroll
            for (int nt = 0; nt < 4; ++nt) {
                f4 c = {0.f, 0.f, 0.f, 0.f};
                c = MFMA(anF[mt].s, hG[nt].s, c);
                if (mt == 0) {
                    cs[nt] += fmaxf(c[0], 0.f) + fmaxf(c[1], 0.f)
                            + fmaxf(c[2], 0.f) + fmaxf(c[3], 0.f);
                } else if (quad == 0) {
                    cs[nt] += fmaxf(c[0], 0.f) + fmaxf(c[1], 0.f) + fmaxf(c[2], 0.f);
                }
            }
        #pragma unroll
        for (int nt = 0; nt < 4; ++nt)
            ps[quad * 64 + nt * 16 + l15] = cs[nt];
        LWAIT();
        float tot = ps[t] + ps[64 + t] + ps[128 + t] + ps[192 + t];
        float mf = (float)mask[g];
        emb[(size_t)g * 64 + t] = tot * (1.f / 19.f) * mf;
        LWAIT();
    }
}

// unpack packed (hi|lo) bf16 h from LDS into hi/lo B-fragments
__device__ __forceinline__ void unpack_h(const int* __restrict__ src,
                                         int l15, int quad,
                                         Frag* __restrict__ BHh,
                                         Frag* __restrict__ BHl)
{
    #pragma unroll
    for (int kt = 0; kt < 2; ++kt) {
        const int4* pp = (const int4*)&src[l15 * 68 + kt * 32 + quad * 8];
        int4 va = pp[0], vb = pp[1];
        BHh[kt].i[0] = (int)__builtin_amdgcn_perm((unsigned)va.y, (unsigned)va.x, 0x05040100u);
        BHh[kt].i[1] = (int)__builtin_amdgcn_perm((unsigned)va.w, (unsigned)va.z, 0x05040100u);
        BHh[kt].i[2] = (int)__builtin_amdgcn_perm((unsigned)vb.y, (unsigned)vb.x, 0x05040100u);
        BHh[kt].i[3] = (int)__builtin_amdgcn_perm((unsigned)vb.w, (unsigned)vb.z, 0x05040100u);
        BHl[kt].i[0] = (int)__builtin_amdgcn_perm((unsigned)va.y, (unsigned)va.x, 0x07060302u);
        BHl[kt].i[1] = (int)__builtin_amdgcn_perm((unsigned)va.w, (unsigned)va.z, 0x07060302u);
        BHl[kt].i[2] = (int)__builtin_amdgcn_perm((unsigned)vb.y, (unsigned)vb.x, 0x07060302u);
        BHl[kt].i[3] = (int)__builtin_amdgcn_perm((unsigned)vb.w, (unsigned)vb.z, 0x07060302u);
    }
}

// ---------------------------------------------------------------------------
// Kernel B v3: both LSTM layers + head via MFMA, LAYER-SPLIT waves.
// 16 blocks x 1024 threads (16 waves); waves 0-7 = layer 0, waves 8-15 =
// layer 1 (lagged 1 step).  Each wave owns 2 gate-tiles of ONE layer ->
// only 8 weight frags (32 VGPR) per wave, pinned via asm so the register
// allocator cannot sink the weight loads back into the loop (R1's failure:
// VGPR_Count=88 proved weights were re-fetched+re-packed every step; per-
// active-CU VALUBusy ~64% was that re-pack, not stalls).
// MFMA accumulator chains split 2-ways (ca/cb + f4 add) to halve dependent-
// MFMA latency.  One barrier per step; h as (hi,lo) bf16 pair (f32-accurate
// recurrent path); verified gate-permuted layout from R1 kept verbatim.
// ---------------------------------------------------------------------------
__global__ __launch_bounds__(1024, 4) void lstm_mfma(
    const float* __restrict__ x,      // (B*T, 64) = emb
    const int*   __restrict__ mask,   // (B, T)
    const float* __restrict__ Wih0, const float* __restrict__ Whh0,
    const float* __restrict__ bih0, const float* __restrict__ bhh0,
    const float* __restrict__ Wih1, const float* __restrict__ Whh1,
    const float* __restrict__ bih1, const float* __restrict__ bhh1,
    const float* __restrict__ fc1_w, const float* __restrict__ fc1_b,
    const float* __restrict__ fc2_w, const float* __restrict__ fc2_b,
    float* __restrict__ out)          // (B, 2)
{
    __shared__ int   h0b[2][16 * 68]; // packed (hi|lo) bf16 h0, [b][u], dbuf
    __shared__ int   h1b[2][16 * 68];
    __shared__ float hlast[16][68];
    __shared__ float red[512];
    __shared__ int   li_s[16];

    const int tid  = threadIdx.x;     // 0..1023
    const int w    = tid >> 6;        // wave 0..15
    const int grp  = w >> 3;          // 0: layer 0, 1: layer 1
    const int wl   = w & 7;           // wave within layer
    const int lane = tid & 63;
    const int l15  = lane & 15;       // batch col
    const int quad = lane >> 4;
    const int bb0  = blockIdx.x * 16;

    // zero h1b[0] (read as BH1=h1(-1)=0 at end of it=0)
    for (int i = tid; i < 16 * 68; i += 1024) h1b[0][i] = 0;

    // ---- lastidx per batch row ----
    if (tid < 512) {
        int b16 = tid >> 5, j = tid & 31;
        int s = 0;
        #pragma unroll
        for (int c8 = 0; c8 < 8; ++c8)
            s += mask[(bb0 + b16) * TT + j + 32 * c8];
        red[tid] = (float)s;
    }
    __syncthreads();
    if (tid < 16) {
        float s = 0.f;
        #pragma unroll
        for (int j = 0; j < 32; ++j) s += red[tid * 32 + j];
        int li = (int)s - 1;
        li_s[tid] = li < 0 ? 0 : (li > TT - 1 ? TT - 1 : li);
    }
    __syncthreads();
    const int li = li_s[l15];

    // ---- this wave's layer weights: 2 gate-tiles, 8 frags = 32 VGPR ----
    // tile-row r maps to orig gate row (r&3)*64 + (mg*4 + (r>>2)); C-frag
    // lane (l15=batch, quad) rows quad*4+r = gates r of unit mg*4+quad.
    const float* __restrict__ Wx = grp ? Wih1 : Wih0;
    const float* __restrict__ Wh = grp ? Whh1 : Whh0;
    const float* __restrict__ bi = grp ? bih1 : bih0;
    const float* __restrict__ bh = grp ? bhh1 : bhh0;

    Frag Ax[2][2], Ah[2][2];
    f4 biasv[2];
    #pragma unroll
    for (int mt = 0; mt < 2; ++mt) {
        int mg = 2 * wl + mt;
        int orig = (l15 & 3) * 64 + (mg * 4 + (l15 >> 2));
        #pragma unroll
        for (int kt = 0; kt < 2; ++kt)
            #pragma unroll
            for (int p = 0; p < 4; ++p) {
                int k = kt * 32 + quad * 8 + 2 * p;
                Ax[mt][kt].i[p] = pkbf(Wx[orig * 64 + k], Wx[orig * 64 + k + 1]);
                Ah[mt][kt].i[p] = pkbf(Wh[orig * 64 + k], Wh[orig * 64 + k + 1]);
            }
        int uu = mg * 4 + quad;
        #pragma unroll
        for (int r = 0; r < 4; ++r)
            biasv[mt][r] = bi[r * 64 + uu] + bh[r * 64 + uu];
    }
    // pin: asm-defined values can't be rematerialized -> stay in VGPRs
    #pragma unroll
    for (int mt = 0; mt < 2; ++mt) {
        PIN8(Ax[mt][0].s); PIN8(Ax[mt][1].s);
        PIN8(Ah[mt][0].s); PIN8(Ah[mt][1].s);
        PINF(biasv[mt]);
    }

    const int u0 = (2 * wl + 0) * 4 + quad;
    const int u1 = (2 * wl + 1) * 4 + quad;

    // ---- state ----
    Frag BX[2], BH0h[2], BH0l[2], BH1h[2], BH1l[2];
    #pragma unroll
    for (int kt = 0; kt < 2; ++kt)
        #pragma unroll
        for (int p = 0; p < 4; ++p) {
            BX[kt].i[p] = 0; BH0h[kt].i[p] = 0; BH0l[kt].i[p] = 0;
            BH1h[kt].i[p] = 0; BH1l[kt].i[p] = 0;
        }
    float cst[2] = {0.f, 0.f}, hlv[2] = {0.f, 0.f};

    const float* __restrict__ xb = x + (size_t)(bb0 + l15) * TT * 64;
    f4 xpre[4];
    if (grp == 0) {
        const f4* p0 = (const f4*)(xb + quad * 8);
        const f4* p1 = (const f4*)(xb + 32 + quad * 8);
        xpre[0] = p0[0]; xpre[1] = p0[1];
        xpre[2] = p1[0]; xpre[3] = p1[1];
    }

    // iteration it: layer 0 does step it; layer 1 does step it-1.
    #pragma unroll 1
    for (int it = 0; it <= TT; ++it) {
        const int cur = it & 1;
        f4 g[2];
        bool act = false;

        if (grp == 0) {
            if (it < TT) {
                act = true;
                // pack X(it) from prefetch regs (single bf16, as verified)
                #pragma unroll
                for (int kt = 0; kt < 2; ++kt) {
                    f4 v0 = xpre[kt * 2], v1 = xpre[kt * 2 + 1];
                    BX[kt].i[0] = pkbf(v0.x, v0.y);
                    BX[kt].i[1] = pkbf(v0.z, v0.w);
                    BX[kt].i[2] = pkbf(v1.x, v1.y);
                    BX[kt].i[3] = pkbf(v1.z, v1.w);
                }
                // issue X(it+1) prefetch (in flight across the whole step)
                int tn = it + 1 < TT ? it + 1 : TT - 1;
                const f4* p0 = (const f4*)(xb + (size_t)tn * 64 + quad * 8);
                const f4* p1 = (const f4*)(xb + (size_t)tn * 64 + 32 + quad * 8);
                xpre[0] = p0[0]; xpre[1] = p0[1];
                xpre[2] = p1[0]; xpre[3] = p1[1];

                #pragma unroll
                for (int mt = 0; mt < 2; ++mt) {
                    f4 ca = biasv[mt];
                    ca = MFMA(Ax[mt][0].s, BX[0].s,   ca);
                    ca = MFMA(Ah[mt][0].s, BH0h[0].s, ca);
                    ca = MFMA(Ah[mt][0].s, BH0l[0].s, ca);
                    f4 cb = {0.f, 0.f, 0.f, 0.f};
                    cb = MFMA(Ax[mt][1].s, BX[1].s,   cb);
                    cb = MFMA(Ah[mt][1].s, BH0h[1].s, cb);
                    cb = MFMA(Ah[mt][1].s, BH0l[1].s, cb);
                    g[mt] = ca + cb;
                }
            }
        } else {
            if (it >= 1) {
                act = true;
                #pragma unroll
                for (int mt = 0; mt < 2; ++mt) {
                    f4 ca = biasv[mt];
                    ca = MFMA(Ax[mt][0].s, BH0h[0].s, ca);
                    ca = MFMA(Ax[mt][0].s, BH0l[0].s, ca);
                    ca = MFMA(Ah[mt][0].s, BH1h[0].s, ca);
                    ca = MFMA(Ah[mt][0].s, BH1l[0].s, ca);
                    f4 cb = {0.f, 0.f, 0.f, 0.f};
                    cb = MFMA(Ax[mt][1].s, BH0h[1].s, cb);
                    cb = MFMA(Ax[mt][1].s, BH0l[1].s, cb);
                    cb = MFMA(Ah[mt][1].s, BH1h[1].s, cb);
                    cb = MFMA(Ah[mt][1].s, BH1l[1].s, cb);
                    g[mt] = ca + cb;
                }
            }
        }

        if (act) {
            int* __restrict__ dst = grp ? h1b[cur] : h0b[cur];
            #pragma unroll
            for (int mt = 0; mt < 2; ++mt) {
                f4 gg = g[mt];
                float si = sigm(gg[0]), sf = sigm(gg[1]);
                float tg = tanha(gg[2]), so = sigm(gg[3]);
                float cc = fmaf(sf, cst[mt], si * tg);
                cst[mt] = cc;
                float h = so * tanha(cc);
                if (grp && it - 1 == li) hlv[mt] = h;
                unsigned hb = __float_as_uint(h);
                float hhi = __uint_as_float(hb & 0xFFFF0000u);
                float hlo = h - hhi;
                unsigned lopk = (unsigned)pkbf(hlo, hlo);
                int packed = (int)__builtin_amdgcn_perm(lopk, hb, 0x05040302u);
                dst[l15 * 68 + (mt ? u1 : u0)] = packed;
            }
        }

        WGBAR();   // lgkmcnt(0)+s_barrier; X prefetch stays in flight

        if (it < TT) {
            unpack_h(h0b[cur], l15, quad, BH0h, BH0l);
            if (grp) unpack_h(h1b[cur], l15, quad, BH1h, BH1l);
        }
    }

    // ---- head ----
    if (grp == 1) {
        hlast[l15][u0] = hlv[0];
        hlast[l15][u1] = hlv[1];
    }
    __syncthreads();
    if (tid < 512) {
        int b = tid >> 5, o = tid & 31;
        float acc = fc1_b[o];
        const float* fw = fc1_w + o * 64;
        #pragma unroll
        for (int j = 0; j < 64; ++j)
            acc = fmaf(hlast[b][j], fw[j], acc);
        red[b * 32 + o] = fmaxf(acc, 0.f);
    }
    __syncthreads();
    if (tid < 32) {
        int b = tid >> 1, o = tid & 1;
        float acc = fc2_b[o];
        #pragma unroll
        for (int j = 0; j < 32; ++j)
            acc = fmaf(fc2_w[o * 32 + j], red[b * 32 + j], acc);
        out[(bb0 + b) * 2 + o] = acc;
    }
}

// ---------------------------------------------------------------------------
extern "C" void kernel_launch(void* const* d_in, const int* in_sizes, int n_in,
                              void* d_out, int out_size, void* d_ws, size_t ws_size,
                              hipStream_t stream)
{
    const float* conn  = (const float*)d_in[0];
    const int*   mask  = (const int*)  d_in[1];
    const float* w1_w  = (const float*)d_in[2];
    const float* w1_b  = (const float*)d_in[3];
    const float* w2_w  = (const float*)d_in[4];
    const float* w2_b  = (const float*)d_in[5];
    const float* Wih0  = (const float*)d_in[6];
    const float* Whh0  = (const float*)d_in[7];
    const float* bih0  = (const float*)d_in[8];
    const float* bhh0  = (const float*)d_in[9];
    const float* Wih1  = (const float*)d_in[10];
    const float* Whh1  = (const float*)d_in[11];
    const float* bih1  = (const float*)d_in[12];
    const float* bhh1  = (const float*)d_in[13];
    const float* fc1_w = (const float*)d_in[14];
    const float* fc1_b = (const float*)d_in[15];
    const float* fc2_w = (const float*)d_in[16];
    const float* fc2_b = (const float*)d_in[17];

    float* out = (float*)d_out;
    float* emb = (float*)d_ws;        // 16.8 MB

    const int num_graphs = BB * TT;

    encoder_mfma<<<8192, 64, 0, stream>>>(
        conn, mask, w1_w, w1_b, w2_w, w2_b, emb, num_graphs);

    lstm_mfma<<<16, 1024, 0, stream>>>(
        emb, mask, Wih0, Whh0, bih0, bhh0, Wih1, Whh1, bih1, bhh1,
        fc1_w, fc1_b, fc2_w, fc2_b, out);
}

// Round 4
// 589.040 us; speedup vs baseline: 1.0481x; 1.0250x over previous
//
#include <hip/hip_runtime.h>
#include <hip/hip_bf16.h>
#include <math.h>

#define GN 19            // graph nodes
#define BB 256
#define TT 256

typedef short short8 __attribute__((ext_vector_type(8)));
typedef float f4 __attribute__((ext_vector_type(4)));
typedef unsigned short u16;

union Frag { int i[4]; short8 s; };

// wave-local LDS ordering fence: wait LDS ops, NO vmcnt drain, no barrier.
#define LWAIT() __asm__ volatile("s_waitcnt lgkmcnt(0)" ::: "memory")
// workgroup barrier WITHOUT vmcnt(0) drain: global loads stay in flight.
#define WGBAR() __asm__ volatile("s_waitcnt lgkmcnt(0)\ns_barrier" ::: "memory")
// opaque-register pin
#define PIN8(x) __asm__ volatile("" : "+v"(x))
#define PINF(x) __asm__ volatile("" : "+v"(x))

#define MFMA(a,b,c) __builtin_amdgcn_mfma_f32_16x16x32_bf16(a,b,c,0,0,0)

// packed RNE float pair -> bf16 pair (v_cvt_pk_bf16_f32 on gfx950)
__device__ __forceinline__ int pkbf(float a, float b) {
    __hip_bfloat162 h2 = __float22bfloat162_rn(make_float2(a, b));
    union { __hip_bfloat162 h; int i; } u; u.h = h2; return u.i;
}

__device__ __forceinline__ float fexp2(float x) { return __builtin_amdgcn_exp2f(x); }
__device__ __forceinline__ float frcp(float x)  { return __builtin_amdgcn_rcpf(x); }
__device__ __forceinline__ float sigm(float x)  { return frcp(1.f + fexp2(-1.4426950408889634f * x)); }
__device__ __forceinline__ float tanha(float x) { float e = fexp2(2.8853900817779268f * x); return 1.f - 2.f * frcp(e + 1.f); }

// ---------------------------------------------------------------------------
// Kernel A: graph encoder via bf16 MFMA (16x16x32).  Only change vs R2:
// emb is written as bf16 (RNE via v_cvt_pk_bf16_f32) — numerically identical
// to the LSTM's previous pkbf(X) conversion, halves emb traffic, and lets
// the LSTM load X B-fragments directly with no per-step conversion.
// ---------------------------------------------------------------------------
__global__ __launch_bounds__(64) void encoder_mfma(
    const float* __restrict__ conn,   // (G,19,19)
    const int*   __restrict__ mask,   // (G)
    const float* __restrict__ w1_w,   // (64,19)
    const float* __restrict__ w1_b,   // (64)
    const float* __restrict__ w2_w,   // (64,64)
    const float* __restrict__ w2_b,   // (64)
    u16* __restrict__ emb,            // (G,64) bf16
    int num_graphs)
{
    __shared__ float S[2304];         // 9216 B, reused 4 ways
    __shared__ float dis[32];
    __shared__ float ps[256];

    const int t = threadIdx.x;
    const int l15 = t & 15;
    const int quad = t >> 4;

    float km[8];
    #pragma unroll
    for (int j = 0; j < 8; ++j) km[j] = (quad * 8 + j < GN) ? 1.f : 0.f;

    int rr[6], cc[6];
    #pragma unroll
    for (int i = 0; i < 6; ++i) {
        int e = t + 64 * i;
        rr[i] = e / GN;
        cc[i] = e - rr[i] * GN;
    }

    Frag w1F[4];
    #pragma unroll
    for (int nt = 0; nt < 4; ++nt) {
        int n = nt * 16 + l15;
        #pragma unroll
        for (int p = 0; p < 4; ++p) {
            int k0 = quad * 8 + 2 * p, k1 = k0 + 1;
            float a = (k0 < GN) ? w1_w[n * GN + k0] : 0.f;
            float b = (k1 < GN) ? w1_w[n * GN + k1] : 0.f;
            w1F[nt].i[p] = pkbf(a, b);
        }
    }
    Frag w2F[2][4];
    #pragma unroll
    for (int kt = 0; kt < 2; ++kt)
        #pragma unroll
        for (int nt = 0; nt < 4; ++nt) {
            int n = nt * 16 + l15;
            #pragma unroll
            for (int p = 0; p < 4; ++p) {
                int k = kt * 32 + quad * 8 + 2 * p;
                w2F[kt][nt].i[p] = pkbf(w2_w[n * 64 + k], w2_w[n * 64 + k + 1]);
            }
        }
    float b1v[4], b2v[4];
    #pragma unroll
    for (int nt = 0; nt < 4; ++nt) {
        b1v[nt] = w1_b[nt * 16 + l15];
        b2v[nt] = w2_b[nt * 16 + l15];
    }

    float pf[6];
    {
        int g0 = blockIdx.x < num_graphs ? blockIdx.x : 0;
        const float* Ag = conn + (size_t)g0 * (GN * GN);
        #pragma unroll
        for (int i = 0; i < 6; ++i) {
            int e = t + 64 * i;
            if (e < GN * GN) pf[i] = Ag[e];
        }
    }

    #pragma unroll 1
    for (int g = blockIdx.x; g < num_graphs; g += gridDim.x) {
        #pragma unroll
        for (int i = 0; i < 4; ++i) {
            int s = t + 64 * i;
            int row = s >> 3, c4 = s & 7;
            f4 z = {0.f, 0.f, 0.f, 0.f};
            *(f4*)&S[row * 68 + c4 * 4] = z;
        }
        LWAIT();
        #pragma unroll
        for (int i = 0; i < 6; ++i) {
            if (t + 64 * i < GN * GN) S[rr[i] * 68 + cc[i]] = pf[i];
        }
        {
            int gn = g + gridDim.x;
            const float* Ag = conn + (size_t)(gn < num_graphs ? gn : g) * (GN * GN);
            #pragma unroll
            for (int i = 0; i < 6; ++i) {
                int e = t + 64 * i;
                if (e < GN * GN) pf[i] = Ag[e];
            }
        }
        LWAIT();

        if (t < 32) {
            float dv = 0.f;
            if (t < GN) {
                float d = 1.0f;
                #pragma unroll
                for (int c4 = 0; c4 < 8; ++c4) {
                    f4 v = *(f4*)&S[t * 68 + c4 * 4];
                    d += v.x + v.y + v.z + v.w;
                }
                dv = rsqrtf(d);
            }
            dis[t] = dv;
        }
        LWAIT();

        float dk[8];
        {
            f4 v0 = *(f4*)&dis[quad * 8];
            f4 v1 = *(f4*)&dis[quad * 8 + 4];
            dk[0]=v0.x; dk[1]=v0.y; dk[2]=v0.z; dk[3]=v0.w;
            dk[4]=v1.x; dk[5]=v1.y; dk[6]=v1.z; dk[7]=v1.w;
        }
        Frag aF[2], anF[2];
        #pragma unroll
        for (int mt = 0; mt < 2; ++mt) {
            int m = l15 + 16 * mt;
            float dm = dis[m];
            f4 v0 = *(f4*)&S[m * 68 + quad * 8];
            f4 v1 = *(f4*)&S[m * 68 + quad * 8 + 4];
            float av[8] = {v0.x, v0.y, v0.z, v0.w, v1.x, v1.y, v1.z, v1.w};
            float an[8];
            #pragma unroll
            for (int j = 0; j < 8; ++j) {
                int k = quad * 8 + j;
                an[j] = (av[j] + (m == k ? 1.f : 0.f)) * dm * dk[j];
            }
            #pragma unroll
            for (int p = 0; p < 4; ++p) {
                aF[mt].i[p]  = pkbf(av[2*p], av[2*p+1]);
                anF[mt].i[p] = pkbf(an[2*p], an[2*p+1]);
            }
        }
        LWAIT();

        #pragma unroll
        for (int mt = 0; mt < 2; ++mt)
            #pragma unroll
            for (int nt = 0; nt < 4; ++nt) {
                float bb = b1v[nt];
                f4 c = {bb, bb, bb, bb};
                c = MFMA(aF[mt].s, w1F[nt].s, c);
                int col = nt * 16 + l15;
                #pragma unroll
                for (int r = 0; r < 4; ++r)
                    S[col * 36 + (mt * 16 + quad * 4 + r)] = c[r];
            }
        LWAIT();

        Frag hF[4];
        #pragma unroll
        for (int nt = 0; nt < 4; ++nt) {
            int n = nt * 16 + l15;
            f4 v0 = *(f4*)&S[n * 36 + quad * 8];
            f4 v1 = *(f4*)&S[n * 36 + quad * 8 + 4];
            float vv[8] = {v0.x, v0.y, v0.z, v0.w, v1.x, v1.y, v1.z, v1.w};
            #pragma unroll
            for (int p = 0; p < 4; ++p)
                hF[nt].i[p] = pkbf(vv[2*p] * km[2*p], vv[2*p+1] * km[2*p+1]);
        }
        LWAIT();

        #pragma unroll
        for (int mt = 0; mt < 2; ++mt)
            #pragma unroll
            for (int nt = 0; nt < 4; ++nt) {
                f4 c = {0.f, 0.f, 0.f, 0.f};
                c = MFMA(anF[mt].s, hF[nt].s, c);
                int col = nt * 16 + l15;
                #pragma unroll
                for (int r = 0; r < 4; ++r)
                    S[(mt * 16 + quad * 4 + r) * 68 + col] = fmaxf(c[r], 0.f);
            }
        LWAIT();

        Frag xF[2][2];
        #pragma unroll
        for (int mt = 0; mt < 2; ++mt) {
            int m = l15 + 16 * mt;
            #pragma unroll
            for (int kt = 0; kt < 2; ++kt) {
                f4 v0 = *(f4*)&S[m * 68 + kt * 32 + quad * 8];
                f4 v1 = *(f4*)&S[m * 68 + kt * 32 + quad * 8 + 4];
                xF[mt][kt].i[0] = pkbf(v0.x, v0.y);
                xF[mt][kt].i[1] = pkbf(v0.z, v0.w);
                xF[mt][kt].i[2] = pkbf(v1.x, v1.y);
                xF[mt][kt].i[3] = pkbf(v1.z, v1.w);
            }
        }
        LWAIT();

        #pragma unroll
        for (int mt = 0; mt < 2; ++mt)
            #pragma unroll
            for (int nt = 0; nt < 4; ++nt) {
                float bb = b2v[nt];
                f4 c = {bb, bb, bb, bb};
                c = MFMA(xF[mt][0].s, w2F[0][nt].s, c);
                c = MFMA(xF[mt][1].s, w2F[1][nt].s, c);
                int col = nt * 16 + l15;
                #pragma unroll
                for (int r = 0; r < 4; ++r)
                    S[col * 36 + (mt * 16 + quad * 4 + r)] = c[r];
            }
        LWAIT();

        Frag hG[4];
        #pragma unroll
        for (int nt = 0; nt < 4; ++nt) {
            int n = nt * 16 + l15;
            f4 v0 = *(f4*)&S[n * 36 + quad * 8];
            f4 v1 = *(f4*)&S[n * 36 + quad * 8 + 4];
            float vv[8] = {v0.x, v0.y, v0.z, v0.w, v1.x, v1.y, v1.z, v1.w};
            #pragma unroll
            for (int p = 0; p < 4; ++p)
                hG[nt].i[p] = pkbf(vv[2*p] * km[2*p], vv[2*p+1] * km[2*p+1]);
        }

        float cs[4];
        #pragma unroll
        for (int nt = 0; nt < 4; ++nt) cs[nt] = 0.f;
        #pragma unroll
        for (int mt = 0; mt < 2; ++mt)
            #pragma unroll
            for (int nt = 0; nt < 4; ++nt) {
                f4 c = {0.f, 0.f, 0.f, 0.f};
                c = MFMA(anF[mt].s, hG[nt].s, c);
                if (mt == 0) {
                    cs[nt] += fmaxf(c[0], 0.f) + fmaxf(c[1], 0.f)
                            + fmaxf(c[2], 0.f) + fmaxf(c[3], 0.f);
                } else if (quad == 0) {
                    cs[nt] += fmaxf(c[0], 0.f) + fmaxf(c[1], 0.f) + fmaxf(c[2], 0.f);
                }
            }
        #pragma unroll
        for (int nt = 0; nt < 4; ++nt)
            ps[quad * 64 + nt * 16 + l15] = cs[nt];
        LWAIT();
        float tot = ps[t] + ps[64 + t] + ps[128 + t] + ps[192 + t];
        float mf = (float)mask[g];
        float v = tot * (1.f / 19.f) * mf;
        emb[(size_t)g * 64 + t] = (u16)(unsigned)pkbf(v, v);  // low16 = bf16RNE(v)
        LWAIT();
    }
}

// read hi/lo bf16 B-fragments straight from LDS (zero VALU: layout is
// already B-fragment-natural: [batch][unit], units contiguous)
__device__ __forceinline__ void read_h2(const u16* __restrict__ hi,
                                        const u16* __restrict__ lo,
                                        int off, Frag* __restrict__ BHh,
                                        Frag* __restrict__ BHl)
{
    #pragma unroll
    for (int kt = 0; kt < 2; ++kt) {
        int4 vh = *(const int4*)&hi[off + kt * 32];
        int4 vl = *(const int4*)&lo[off + kt * 32];
        BHh[kt].i[0] = vh.x; BHh[kt].i[1] = vh.y; BHh[kt].i[2] = vh.z; BHh[kt].i[3] = vh.w;
        BHl[kt].i[0] = vl.x; BHl[kt].i[1] = vl.y; BHl[kt].i[2] = vl.z; BHl[kt].i[3] = vl.w;
    }
}

// ---------------------------------------------------------------------------
// Kernel B v4: both LSTM layers + head via MFMA, layer-split waves.
// Changes vs R2 (which landed at 328us, VGPR=64 -> allocator spilled weights
// to scratch chasing 8 waves/EU; per-active-CU VALUBusy 73% was spill reload
// + perm/pack work):
//  1. amdgpu_waves_per_eu(4,4): occupancy capped at what we actually launch
//     (16 waves/CU) -> no incentive to shrink below 128 VGPR -> weight frags
//     (32 VGPR/wave) stay resident.
//  2. h exchange as SEPARATE hi/lo bf16 arrays, [batch][unit] row stride 72
//     (144B, 16B aligned, bank-balanced): B-frag unpack = pure ds_read_b128,
//     the 16-32 v_perm/step/wave are gone.  Producer writes 4 ds_write_b16.
//  3. X arrives as bf16 from the encoder: B-frags load directly as int4;
//     the 8 pkbf/step are gone; emb traffic halved.
// ---------------------------------------------------------------------------
__global__ __launch_bounds__(1024) __attribute__((amdgpu_waves_per_eu(4, 4)))
void lstm_mfma(
    const u16*   __restrict__ x,      // (B*T, 64) bf16 = emb
    const int*   __restrict__ mask,   // (B, T)
    const float* __restrict__ Wih0, const float* __restrict__ Whh0,
    const float* __restrict__ bih0, const float* __restrict__ bhh0,
    const float* __restrict__ Wih1, const float* __restrict__ Whh1,
    const float* __restrict__ bih1, const float* __restrict__ bhh1,
    const float* __restrict__ fc1_w, const float* __restrict__ fc1_b,
    const float* __restrict__ fc2_w, const float* __restrict__ fc2_b,
    float* __restrict__ out)          // (B, 2)
{
    // row stride 72 units (144B): 16B-aligned rows, banks (4(b+q)+d)%32 ->
    // 8 dwords/bank/access, perfectly balanced.
    __shared__ __attribute__((aligned(16))) u16 h0hi[2][16 * 72];
    __shared__ __attribute__((aligned(16))) u16 h0lo[2][16 * 72];
    __shared__ __attribute__((aligned(16))) u16 h1hi[2][16 * 72];
    __shared__ __attribute__((aligned(16))) u16 h1lo[2][16 * 72];
    __shared__ float hlast[16][68];
    __shared__ float red[512];
    __shared__ int   li_s[16];

    const int tid  = threadIdx.x;     // 0..1023
    const int w    = tid >> 6;        // wave 0..15
    const int grp  = w >> 3;          // 0: layer 0, 1: layer 1
    const int wl   = w & 7;           // wave within layer
    const int lane = tid & 63;
    const int l15  = lane & 15;       // batch col
    const int quad = lane >> 4;
    const int bb0  = blockIdx.x * 16;

    // zero h1 dbuf[0] (read as h1(-1)=0 after it=0's barrier)
    for (int i = tid; i < 16 * 72; i += 1024) { h1hi[0][i] = 0; h1lo[0][i] = 0; }

    // ---- lastidx per batch row ----
    if (tid < 512) {
        int b16 = tid >> 5, j = tid & 31;
        int s = 0;
        #pragma unroll
        for (int c8 = 0; c8 < 8; ++c8)
            s += mask[(bb0 + b16) * TT + j + 32 * c8];
        red[tid] = (float)s;
    }
    __syncthreads();
    if (tid < 16) {
        float s = 0.f;
        #pragma unroll
        for (int j = 0; j < 32; ++j) s += red[tid * 32 + j];
        int li = (int)s - 1;
        li_s[tid] = li < 0 ? 0 : (li > TT - 1 ? TT - 1 : li);
    }
    __syncthreads();
    const int li = li_s[l15];

    // ---- this wave's layer weights: 2 gate-tiles, 8 frags = 32 VGPR ----
    const float* __restrict__ Wx = grp ? Wih1 : Wih0;
    const float* __restrict__ Wh = grp ? Whh1 : Whh0;
    const float* __restrict__ bi = grp ? bih1 : bih0;
    const float* __restrict__ bh = grp ? bhh1 : bhh0;

    Frag Ax[2][2], Ah[2][2];
    f4 biasv[2];
    #pragma unroll
    for (int mt = 0; mt < 2; ++mt) {
        int mg = 2 * wl + mt;
        int orig = (l15 & 3) * 64 + (mg * 4 + (l15 >> 2));
        #pragma unroll
        for (int kt = 0; kt < 2; ++kt)
            #pragma unroll
            for (int p = 0; p < 4; ++p) {
                int k = kt * 32 + quad * 8 + 2 * p;
                Ax[mt][kt].i[p] = pkbf(Wx[orig * 64 + k], Wx[orig * 64 + k + 1]);
                Ah[mt][kt].i[p] = pkbf(Wh[orig * 64 + k], Wh[orig * 64 + k + 1]);
            }
        int uu = mg * 4 + quad;
        #pragma unroll
        for (int r = 0; r < 4; ++r)
            biasv[mt][r] = bi[r * 64 + uu] + bh[r * 64 + uu];
    }
    #pragma unroll
    for (int mt = 0; mt < 2; ++mt) {
        PIN8(Ax[mt][0].s); PIN8(Ax[mt][1].s);
        PIN8(Ah[mt][0].s); PIN8(Ah[mt][1].s);
        PINF(biasv[mt]);
    }

    const int u0 = (2 * wl + 0) * 4 + quad;
    const int u1 = (2 * wl + 1) * 4 + quad;
    const int hoff = l15 * 72 + quad * 8;   // B-frag read base (units quad*8)

    // ---- state ----
    Frag BH0h[2], BH0l[2], BH1h[2], BH1l[2], BXn[2];
    #pragma unroll
    for (int kt = 0; kt < 2; ++kt)
        #pragma unroll
        for (int p = 0; p < 4; ++p) {
            BXn[kt].i[p] = 0; BH0h[kt].i[p] = 0; BH0l[kt].i[p] = 0;
            BH1h[kt].i[p] = 0; BH1l[kt].i[p] = 0;
        }
    float cst[2] = {0.f, 0.f}, hlv[2] = {0.f, 0.f};

    const u16* __restrict__ xb = x + (size_t)(bb0 + l15) * TT * 64;
    if (grp == 0) {
        // prefetch X(0): B-frags load directly (bf16 pairs already packed)
        BXn[0] = *(const Frag*)&xb[quad * 8];
        BXn[1] = *(const Frag*)&xb[32 + quad * 8];
    }

    // iteration it: layer 0 does step it; layer 1 does step it-1.
    #pragma unroll 1
    for (int it = 0; it <= TT; ++it) {
        const int cur = it & 1;
        f4 g[2];
        bool act = false;

        if (grp == 0) {
            if (it < TT) {
                act = true;
                Frag bx0 = BXn[0], bx1 = BXn[1];
                // issue X(it+1) prefetch (in flight across the whole step)
                int tn = it + 1 < TT ? it + 1 : TT - 1;
                BXn[0] = *(const Frag*)&xb[(size_t)tn * 64 + quad * 8];
                BXn[1] = *(const Frag*)&xb[(size_t)tn * 64 + 32 + quad * 8];

                #pragma unroll
                for (int mt = 0; mt < 2; ++mt) {
                    f4 ca = biasv[mt];
                    ca = MFMA(Ax[mt][0].s, bx0.s,      ca);
                    ca = MFMA(Ah[mt][0].s, BH0h[0].s,  ca);
                    ca = MFMA(Ah[mt][0].s, BH0l[0].s,  ca);
                    f4 cb = {0.f, 0.f, 0.f, 0.f};
                    cb = MFMA(Ax[mt][1].s, bx1.s,      cb);
                    cb = MFMA(Ah[mt][1].s, BH0h[1].s,  cb);
                    cb = MFMA(Ah[mt][1].s, BH0l[1].s,  cb);
                    g[mt] = ca + cb;
                }
            }
        } else {
            if (it >= 1) {
                act = true;
                #pragma unroll
                for (int mt = 0; mt < 2; ++mt) {
                    f4 ca = biasv[mt];
                    ca = MFMA(Ax[mt][0].s, BH0h[0].s, ca);
                    ca = MFMA(Ax[mt][0].s, BH0l[0].s, ca);
                    ca = MFMA(Ah[mt][0].s, BH1h[0].s, ca);
                    ca = MFMA(Ah[mt][0].s, BH1l[0].s, ca);
                    f4 cb = {0.f, 0.f, 0.f, 0.f};
                    cb = MFMA(Ax[mt][1].s, BH0h[1].s, cb);
                    cb = MFMA(Ax[mt][1].s, BH0l[1].s, cb);
                    cb = MFMA(Ah[mt][1].s, BH1h[1].s, cb);
                    cb = MFMA(Ah[mt][1].s, BH1l[1].s, cb);
                    g[mt] = ca + cb;
                }
            }
        }

        if (act) {
            u16* __restrict__ dhi = grp ? h1hi[cur] : h0hi[cur];
            u16* __restrict__ dlo = grp ? h1lo[cur] : h0lo[cur];
            #pragma unroll
            for (int mt = 0; mt < 2; ++mt) {
                f4 gg = g[mt];
                float si = sigm(gg[0]), sf = sigm(gg[1]);
                float tg = tanha(gg[2]), so = sigm(gg[3]);
                float cc = fmaf(sf, cst[mt], si * tg);
                cst[mt] = cc;
                float h = so * tanha(cc);
                if (grp && it - 1 == li) hlv[mt] = h;
                unsigned hb = __float_as_uint(h);
                float hhi = __uint_as_float(hb & 0xFFFF0000u);
                float hlo = h - hhi;
                int uu = mt ? u1 : u0;
                dhi[l15 * 72 + uu] = (u16)(hb >> 16);
                dlo[l15 * 72 + uu] = (u16)(unsigned)pkbf(hlo, hlo);
            }
        }

        WGBAR();   // lgkmcnt(0)+s_barrier; X prefetch stays in flight

        if (it < TT) {
            read_h2(h0hi[cur], h0lo[cur], hoff, BH0h, BH0l);
            if (grp) read_h2(h1hi[cur], h1lo[cur], hoff, BH1h, BH1l);
        }
    }

    // ---- head ----
    if (grp == 1) {
        hlast[l15][u0] = hlv[0];
        hlast[l15][u1] = hlv[1];
    }
    __syncthreads();
    if (tid < 512) {
        int b = tid >> 5, o = tid & 31;
        float acc = fc1_b[o];
        const float* fw = fc1_w + o * 64;
        #pragma unroll
        for (int j = 0; j < 64; ++j)
            acc = fmaf(hlast[b][j], fw[j], acc);
        red[b * 32 + o] = fmaxf(acc, 0.f);
    }
    __syncthreads();
    if (tid < 32) {
        int b = tid >> 1, o = tid & 1;
        float acc = fc2_b[o];
        #pragma unroll
        for (int j = 0; j < 32; ++j)
            acc = fmaf(fc2_w[o * 32 + j], red[b * 32 + j], acc);
        out[(bb0 + b) * 2 + o] = acc;
    }
}

// ---------------------------------------------------------------------------
extern "C" void kernel_launch(void* const* d_in, const int* in_sizes, int n_in,
                              void* d_out, int out_size, void* d_ws, size_t ws_size,
                              hipStream_t stream)
{
    const float* conn  = (const float*)d_in[0];
    const int*   mask  = (const int*)  d_in[1];
    const float* w1_w  = (const float*)d_in[2];
    const float* w1_b  = (const float*)d_in[3];
    const float* w2_w  = (const float*)d_in[4];
    const float* w2_b  = (const float*)d_in[5];
    const float* Wih0  = (const float*)d_in[6];
    const float* Whh0  = (const float*)d_in[7];
    const float* bih0  = (const float*)d_in[8];
    const float* bhh0  = (const float*)d_in[9];
    const float* Wih1  = (const float*)d_in[10];
    const float* Whh1  = (const float*)d_in[11];
    const float* bih1  = (const float*)d_in[12];
    const float* bhh1  = (const float*)d_in[13];
    const float* fc1_w = (const float*)d_in[14];
    const float* fc1_b = (const float*)d_in[15];
    const float* fc2_w = (const float*)d_in[16];
    const float* fc2_b = (const float*)d_in[17];

    float* out = (float*)d_out;
    u16*   emb = (u16*)d_ws;          // 8.4 MB bf16

    const int num_graphs = BB * TT;

    encoder_mfma<<<8192, 64, 0, stream>>>(
        conn, mask, w1_w, w1_b, w2_w, w2_b, emb, num_graphs);

    lstm_mfma<<<16, 1024, 0, stream>>>(
        emb, mask, Wih0, Whh0, bih0, bhh0, Wih1, Whh1, bih1, bhh1,
        fc1_w, fc1_b, fc2_w, fc2_b, out);
}

// Round 5
// 586.012 us; speedup vs baseline: 1.0535x; 1.0052x over previous
//
#include <hip/hip_runtime.h>
#include <hip/hip_bf16.h>
#include <math.h>

#define GN 19            // graph nodes
#define BB 256
#define TT 256

typedef short short8 __attribute__((ext_vector_type(8)));
typedef float f4 __attribute__((ext_vector_type(4)));
typedef unsigned short u16;

union Frag { int i[4]; short8 s; };

// wave-local LDS ordering fence: wait LDS ops, NO vmcnt drain, no barrier.
#define LWAIT() __asm__ volatile("s_waitcnt lgkmcnt(0)" ::: "memory")
// workgroup barrier WITHOUT vmcnt(0) drain: global loads stay in flight.
#define WGBAR() __asm__ volatile("s_waitcnt lgkmcnt(0)\ns_barrier" ::: "memory")
// opaque-register pin
#define PIN8(x) __asm__ volatile("" : "+v"(x))
#define PINF(x) __asm__ volatile("" : "+v"(x))

#define MFMA(a,b,c) __builtin_amdgcn_mfma_f32_16x16x32_bf16(a,b,c,0,0,0)

// packed RNE float pair -> bf16 pair (v_cvt_pk_bf16_f32 on gfx950)
__device__ __forceinline__ int pkbf(float a, float b) {
    __hip_bfloat162 h2 = __float22bfloat162_rn(make_float2(a, b));
    union { __hip_bfloat162 h; int i; } u; u.h = h2; return u.i;
}

__device__ __forceinline__ float fexp2(float x) { return __builtin_amdgcn_exp2f(x); }
__device__ __forceinline__ float frcp(float x)  { return __builtin_amdgcn_rcpf(x); }
__device__ __forceinline__ float sigm(float x)  { return frcp(1.f + fexp2(-1.4426950408889634f * x)); }
__device__ __forceinline__ float tanha(float x) { float e = fexp2(2.8853900817779268f * x); return 1.f - 2.f * frcp(e + 1.f); }

// ---------------------------------------------------------------------------
// Kernel A: graph encoder via bf16 MFMA (16x16x32).  UNCHANGED from R3
// (emb written as bf16).  Will read its counters next round once it
// surfaces in top-5.
// ---------------------------------------------------------------------------
__global__ __launch_bounds__(64) void encoder_mfma(
    const float* __restrict__ conn,   // (G,19,19)
    const int*   __restrict__ mask,   // (G)
    const float* __restrict__ w1_w,   // (64,19)
    const float* __restrict__ w1_b,   // (64)
    const float* __restrict__ w2_w,   // (64,64)
    const float* __restrict__ w2_b,   // (64)
    u16* __restrict__ emb,            // (G,64) bf16
    int num_graphs)
{
    __shared__ float S[2304];         // 9216 B, reused 4 ways
    __shared__ float dis[32];
    __shared__ float ps[256];

    const int t = threadIdx.x;
    const int l15 = t & 15;
    const int quad = t >> 4;

    float km[8];
    #pragma unroll
    for (int j = 0; j < 8; ++j) km[j] = (quad * 8 + j < GN) ? 1.f : 0.f;

    int rr[6], cc[6];
    #pragma unroll
    for (int i = 0; i < 6; ++i) {
        int e = t + 64 * i;
        rr[i] = e / GN;
        cc[i] = e - rr[i] * GN;
    }

    Frag w1F[4];
    #pragma unroll
    for (int nt = 0; nt < 4; ++nt) {
        int n = nt * 16 + l15;
        #pragma unroll
        for (int p = 0; p < 4; ++p) {
            int k0 = quad * 8 + 2 * p, k1 = k0 + 1;
            float a = (k0 < GN) ? w1_w[n * GN + k0] : 0.f;
            float b = (k1 < GN) ? w1_w[n * GN + k1] : 0.f;
            w1F[nt].i[p] = pkbf(a, b);
        }
    }
    Frag w2F[2][4];
    #pragma unroll
    for (int kt = 0; kt < 2; ++kt)
        #pragma unroll
        for (int nt = 0; nt < 4; ++nt) {
            int n = nt * 16 + l15;
            #pragma unroll
            for (int p = 0; p < 4; ++p) {
                int k = kt * 32 + quad * 8 + 2 * p;
                w2F[kt][nt].i[p] = pkbf(w2_w[n * 64 + k], w2_w[n * 64 + k + 1]);
            }
        }
    float b1v[4], b2v[4];
    #pragma unroll
    for (int nt = 0; nt < 4; ++nt) {
        b1v[nt] = w1_b[nt * 16 + l15];
        b2v[nt] = w2_b[nt * 16 + l15];
    }

    float pf[6];
    {
        int g0 = blockIdx.x < num_graphs ? blockIdx.x : 0;
        const float* Ag = conn + (size_t)g0 * (GN * GN);
        #pragma unroll
        for (int i = 0; i < 6; ++i) {
            int e = t + 64 * i;
            if (e < GN * GN) pf[i] = Ag[e];
        }
    }

    #pragma unroll 1
    for (int g = blockIdx.x; g < num_graphs; g += gridDim.x) {
        #pragma unroll
        for (int i = 0; i < 4; ++i) {
            int s = t + 64 * i;
            int row = s >> 3, c4 = s & 7;
            f4 z = {0.f, 0.f, 0.f, 0.f};
            *(f4*)&S[row * 68 + c4 * 4] = z;
        }
        LWAIT();
        #pragma unroll
        for (int i = 0; i < 6; ++i) {
            if (t + 64 * i < GN * GN) S[rr[i] * 68 + cc[i]] = pf[i];
        }
        {
            int gn = g + gridDim.x;
            const float* Ag = conn + (size_t)(gn < num_graphs ? gn : g) * (GN * GN);
            #pragma unroll
            for (int i = 0; i < 6; ++i) {
                int e = t + 64 * i;
                if (e < GN * GN) pf[i] = Ag[e];
            }
        }
        LWAIT();

        if (t < 32) {
            float dv = 0.f;
            if (t < GN) {
                float d = 1.0f;
                #pragma unroll
                for (int c4 = 0; c4 < 8; ++c4) {
                    f4 v = *(f4*)&S[t * 68 + c4 * 4];
                    d += v.x + v.y + v.z + v.w;
                }
                dv = rsqrtf(d);
            }
            dis[t] = dv;
        }
        LWAIT();

        float dk[8];
        {
            f4 v0 = *(f4*)&dis[quad * 8];
            f4 v1 = *(f4*)&dis[quad * 8 + 4];
            dk[0]=v0.x; dk[1]=v0.y; dk[2]=v0.z; dk[3]=v0.w;
            dk[4]=v1.x; dk[5]=v1.y; dk[6]=v1.z; dk[7]=v1.w;
        }
        Frag aF[2], anF[2];
        #pragma unroll
        for (int mt = 0; mt < 2; ++mt) {
            int m = l15 + 16 * mt;
            float dm = dis[m];
            f4 v0 = *(f4*)&S[m * 68 + quad * 8];
            f4 v1 = *(f4*)&S[m * 68 + quad * 8 + 4];
            float av[8] = {v0.x, v0.y, v0.z, v0.w, v1.x, v1.y, v1.z, v1.w};
            float an[8];
            #pragma unroll
            for (int j = 0; j < 8; ++j) {
                int k = quad * 8 + j;
                an[j] = (av[j] + (m == k ? 1.f : 0.f)) * dm * dk[j];
            }
            #pragma unroll
            for (int p = 0; p < 4; ++p) {
                aF[mt].i[p]  = pkbf(av[2*p], av[2*p+1]);
                anF[mt].i[p] = pkbf(an[2*p], an[2*p+1]);
            }
        }
        LWAIT();

        #pragma unroll
        for (int mt = 0; mt < 2; ++mt)
            #pragma unroll
            for (int nt = 0; nt < 4; ++nt) {
                float bb = b1v[nt];
                f4 c = {bb, bb, bb, bb};
                c = MFMA(aF[mt].s, w1F[nt].s, c);
                int col = nt * 16 + l15;
                #pragma unroll
                for (int r = 0; r < 4; ++r)
                    S[col * 36 + (mt * 16 + quad * 4 + r)] = c[r];
            }
        LWAIT();

        Frag hF[4];
        #pragma unroll
        for (int nt = 0; nt < 4; ++nt) {
            int n = nt * 16 + l15;
            f4 v0 = *(f4*)&S[n * 36 + quad * 8];
            f4 v1 = *(f4*)&S[n * 36 + quad * 8 + 4];
            float vv[8] = {v0.x, v0.y, v0.z, v0.w, v1.x, v1.y, v1.z, v1.w};
            #pragma unroll
            for (int p = 0; p < 4; ++p)
                hF[nt].i[p] = pkbf(vv[2*p] * km[2*p], vv[2*p+1] * km[2*p+1]);
        }
        LWAIT();

        #pragma unroll
        for (int mt = 0; mt < 2; ++mt)
            #pragma unroll
            for (int nt = 0; nt < 4; ++nt) {
                f4 c = {0.f, 0.f, 0.f, 0.f};
                c = MFMA(anF[mt].s, hF[nt].s, c);
                int col = nt * 16 + l15;
                #pragma unroll
                for (int r = 0; r < 4; ++r)
                    S[(mt * 16 + quad * 4 + r) * 68 + col] = fmaxf(c[r], 0.f);
            }
        LWAIT();

        Frag xF[2][2];
        #pragma unroll
        for (int mt = 0; mt < 2; ++mt) {
            int m = l15 + 16 * mt;
            #pragma unroll
            for (int kt = 0; kt < 2; ++kt) {
                f4 v0 = *(f4*)&S[m * 68 + kt * 32 + quad * 8];
                f4 v1 = *(f4*)&S[m * 68 + kt * 32 + quad * 8 + 4];
                xF[mt][kt].i[0] = pkbf(v0.x, v0.y);
                xF[mt][kt].i[1] = pkbf(v0.z, v0.w);
                xF[mt][kt].i[2] = pkbf(v1.x, v1.y);
                xF[mt][kt].i[3] = pkbf(v1.z, v1.w);
            }
        }
        LWAIT();

        #pragma unroll
        for (int mt = 0; mt < 2; ++mt)
            #pragma unroll
            for (int nt = 0; nt < 4; ++nt) {
                float bb = b2v[nt];
                f4 c = {bb, bb, bb, bb};
                c = MFMA(xF[mt][0].s, w2F[0][nt].s, c);
                c = MFMA(xF[mt][1].s, w2F[1][nt].s, c);
                int col = nt * 16 + l15;
                #pragma unroll
                for (int r = 0; r < 4; ++r)
                    S[col * 36 + (mt * 16 + quad * 4 + r)] = c[r];
            }
        LWAIT();

        Frag hG[4];
        #pragma unroll
        for (int nt = 0; nt < 4; ++nt) {
            int n = nt * 16 + l15;
            f4 v0 = *(f4*)&S[n * 36 + quad * 8];
            f4 v1 = *(f4*)&S[n * 36 + quad * 8 + 4];
            float vv[8] = {v0.x, v0.y, v0.z, v0.w, v1.x, v1.y, v1.z, v1.w};
            #pragma unroll
            for (int p = 0; p < 4; ++p)
                hG[nt].i[p] = pkbf(vv[2*p] * km[2*p], vv[2*p+1] * km[2*p+1]);
        }

        float cs[4];
        #pragma unroll
        for (int nt = 0; nt < 4; ++nt) cs[nt] = 0.f;
        #pragma unroll
        for (int mt = 0; mt < 2; ++mt)
            #pragma unroll
            for (int nt = 0; nt < 4; ++nt) {
                f4 c = {0.f, 0.f, 0.f, 0.f};
                c = MFMA(anF[mt].s, hG[nt].s, c);
                if (mt == 0) {
                    cs[nt] += fmaxf(c[0], 0.f) + fmaxf(c[1], 0.f)
                            + fmaxf(c[2], 0.f) + fmaxf(c[3], 0.f);
                } else if (quad == 0) {
                    cs[nt] += fmaxf(c[0], 0.f) + fmaxf(c[1], 0.f) + fmaxf(c[2], 0.f);
                }
            }
        #pragma unroll
        for (int nt = 0; nt < 4; ++nt)
            ps[quad * 64 + nt * 16 + l15] = cs[nt];
        LWAIT();
        float tot = ps[t] + ps[64 + t] + ps[128 + t] + ps[192 + t];
        float mf = (float)mask[g];
        float v = tot * (1.f / 19.f) * mf;
        emb[(size_t)g * 64 + t] = (u16)(unsigned)pkbf(v, v);  // low16 = bf16RNE(v)
        LWAIT();
    }
}

// read hi/lo bf16 B-fragments straight from LDS (zero VALU)
__device__ __forceinline__ void read_h2(const u16* __restrict__ hi,
                                        const u16* __restrict__ lo,
                                        int off, Frag* __restrict__ BHh,
                                        Frag* __restrict__ BHl)
{
    #pragma unroll
    for (int kt = 0; kt < 2; ++kt) {
        int4 vh = *(const int4*)&hi[off + kt * 32];
        int4 vl = *(const int4*)&lo[off + kt * 32];
        BHh[kt].i[0] = vh.x; BHh[kt].i[1] = vh.y; BHh[kt].i[2] = vh.z; BHh[kt].i[3] = vh.w;
        BHl[kt].i[0] = vl.x; BHl[kt].i[1] = vl.y; BHl[kt].i[2] = vl.z; BHl[kt].i[3] = vl.w;
    }
}

// ---------------------------------------------------------------------------
// Kernel B v5: both LSTM layers + head via MFMA, FAT layer-split waves.
// R3 counters showed the step is LDS-bound, not VALU-bound: every wave reads
// the FULL h-exchange buffer (B-frag replication), so 16 waves moved 96 KB
// per CU-step (~768 cyc LDS occupancy) + 511 conflict cyc/step.  Fix: HALVE
// the wave count, DOUBLE per-wave M-tiles:
//   8 waves x 512 threads; waves 0-3 = layer 0, waves 4-7 = layer 1 (lag 1);
//   each wave owns 4 gate-tiles (M=64 rows; 16 weight frags + 16 bias).
// LDS reads/CU-step: 48 KB (4x4 + 4x8 b128 reads), conflicts halve, barrier
// syncs 8 waves not 16.  Total MFMA/act work per CU unchanged.
// waves_per_eu(2,2): 1 block/CU -> 2 waves/SIMD, VGPR budget 256 -> the
// ~130-reg live set (weights+state) fits with no spill regardless of
// whether the allocator uses VGPRs or AGPRs (MFMA reads A/B from AGPR).
// ---------------------------------------------------------------------------
__global__ __launch_bounds__(512) __attribute__((amdgpu_waves_per_eu(2, 2)))
void lstm_mfma(
    const u16*   __restrict__ x,      // (B*T, 64) bf16 = emb
    const int*   __restrict__ mask,   // (B, T)
    const float* __restrict__ Wih0, const float* __restrict__ Whh0,
    const float* __restrict__ bih0, const float* __restrict__ bhh0,
    const float* __restrict__ Wih1, const float* __restrict__ Whh1,
    const float* __restrict__ bih1, const float* __restrict__ bhh1,
    const float* __restrict__ fc1_w, const float* __restrict__ fc1_b,
    const float* __restrict__ fc2_w, const float* __restrict__ fc2_b,
    float* __restrict__ out)          // (B, 2)
{
    __shared__ __attribute__((aligned(16))) u16 h0hi[2][16 * 72];
    __shared__ __attribute__((aligned(16))) u16 h0lo[2][16 * 72];
    __shared__ __attribute__((aligned(16))) u16 h1hi[2][16 * 72];
    __shared__ __attribute__((aligned(16))) u16 h1lo[2][16 * 72];
    __shared__ float hlast[16][68];
    __shared__ float red[512];
    __shared__ int   li_s[16];

    const int tid  = threadIdx.x;     // 0..511
    const int w    = tid >> 6;        // wave 0..7
    const int grp  = w >> 2;          // 0: layer 0 (waves 0-3), 1: layer 1
    const int wl   = w & 3;           // wave within layer
    const int lane = tid & 63;
    const int l15  = lane & 15;       // batch col
    const int quad = lane >> 4;
    const int bb0  = blockIdx.x * 16;

    // zero h1 dbuf[0] (read as h1(-1)=0 after it=0's barrier)
    for (int i = tid; i < 16 * 72; i += 512) { h1hi[0][i] = 0; h1lo[0][i] = 0; }

    // ---- lastidx per batch row ----
    {
        int b16 = tid >> 5, j = tid & 31;
        int s = 0;
        #pragma unroll
        for (int c8 = 0; c8 < 8; ++c8)
            s += mask[(bb0 + b16) * TT + j + 32 * c8];
        red[tid] = (float)s;
    }
    __syncthreads();
    if (tid < 16) {
        float s = 0.f;
        #pragma unroll
        for (int j = 0; j < 32; ++j) s += red[tid * 32 + j];
        int li = (int)s - 1;
        li_s[tid] = li < 0 ? 0 : (li > TT - 1 ? TT - 1 : li);
    }
    __syncthreads();
    const int li = li_s[l15];

    // ---- this wave's layer weights: 4 gate-tiles, 16 frags = 64 regs ----
    // tile-row r of tile mg maps to orig gate row (r&3)*64 + (mg*4+(r>>2));
    // C-frag lane (l15=batch, quad): rows quad*4+r = gates r of unit mg*4+quad.
    const float* __restrict__ Wx = grp ? Wih1 : Wih0;
    const float* __restrict__ Wh = grp ? Whh1 : Whh0;
    const float* __restrict__ bi = grp ? bih1 : bih0;
    const float* __restrict__ bh = grp ? bhh1 : bhh0;

    Frag Ax[4][2], Ah[4][2];
    f4 biasv[4];
    #pragma unroll
    for (int mt = 0; mt < 4; ++mt) {
        int mg = 4 * wl + mt;
        int orig = (l15 & 3) * 64 + (mg * 4 + (l15 >> 2));
        #pragma unroll
        for (int kt = 0; kt < 2; ++kt)
            #pragma unroll
            for (int p = 0; p < 4; ++p) {
                int k = kt * 32 + quad * 8 + 2 * p;
                Ax[mt][kt].i[p] = pkbf(Wx[orig * 64 + k], Wx[orig * 64 + k + 1]);
                Ah[mt][kt].i[p] = pkbf(Wh[orig * 64 + k], Wh[orig * 64 + k + 1]);
            }
        int uu = mg * 4 + quad;
        #pragma unroll
        for (int r = 0; r < 4; ++r)
            biasv[mt][r] = bi[r * 64 + uu] + bh[r * 64 + uu];
    }
    #pragma unroll
    for (int mt = 0; mt < 4; ++mt) {
        PIN8(Ax[mt][0].s); PIN8(Ax[mt][1].s);
        PIN8(Ah[mt][0].s); PIN8(Ah[mt][1].s);
        PINF(biasv[mt]);
    }

    // unit owned by (mt, quad): 16*wl + 4*mt + quad
    const int ubase = 16 * wl + quad;
    const int hoff = l15 * 72 + quad * 8;   // B-frag read base

    // ---- state ----
    Frag BH0h[2], BH0l[2], BH1h[2], BH1l[2], BXn[2];
    #pragma unroll
    for (int kt = 0; kt < 2; ++kt)
        #pragma unroll
        for (int p = 0; p < 4; ++p) {
            BXn[kt].i[p] = 0; BH0h[kt].i[p] = 0; BH0l[kt].i[p] = 0;
            BH1h[kt].i[p] = 0; BH1l[kt].i[p] = 0;
        }
    float cst[4] = {0.f, 0.f, 0.f, 0.f};
    float hlv[4] = {0.f, 0.f, 0.f, 0.f};

    const u16* __restrict__ xb = x + (size_t)(bb0 + l15) * TT * 64;
    if (grp == 0) {
        BXn[0] = *(const Frag*)&xb[quad * 8];
        BXn[1] = *(const Frag*)&xb[32 + quad * 8];
    }

    // iteration it: layer 0 does step it; layer 1 does step it-1.
    #pragma unroll 1
    for (int it = 0; it <= TT; ++it) {
        const int cur = it & 1;
        f4 g[4];
        bool act = false;

        if (grp == 0) {
            if (it < TT) {
                act = true;
                Frag bx0 = BXn[0], bx1 = BXn[1];
                int tn = it + 1 < TT ? it + 1 : TT - 1;
                BXn[0] = *(const Frag*)&xb[(size_t)tn * 64 + quad * 8];
                BXn[1] = *(const Frag*)&xb[(size_t)tn * 64 + 32 + quad * 8];

                #pragma unroll
                for (int mt = 0; mt < 4; ++mt) {
                    f4 ca = biasv[mt];
                    ca = MFMA(Ax[mt][0].s, bx0.s,      ca);
                    ca = MFMA(Ah[mt][0].s, BH0h[0].s,  ca);
                    ca = MFMA(Ah[mt][0].s, BH0l[0].s,  ca);
                    f4 cb = {0.f, 0.f, 0.f, 0.f};
                    cb = MFMA(Ax[mt][1].s, bx1.s,      cb);
                    cb = MFMA(Ah[mt][1].s, BH0h[1].s,  cb);
                    cb = MFMA(Ah[mt][1].s, BH0l[1].s,  cb);
                    g[mt] = ca + cb;
                }
            }
        } else {
            if (it >= 1) {
                act = true;
                #pragma unroll
                for (int mt = 0; mt < 4; ++mt) {
                    f4 ca = biasv[mt];
                    ca = MFMA(Ax[mt][0].s, BH0h[0].s, ca);
                    ca = MFMA(Ax[mt][0].s, BH0l[0].s, ca);
                    ca = MFMA(Ah[mt][0].s, BH1h[0].s, ca);
                    ca = MFMA(Ah[mt][0].s, BH1l[0].s, ca);
                    f4 cb = {0.f, 0.f, 0.f, 0.f};
                    cb = MFMA(Ax[mt][1].s, BH0h[1].s, cb);
                    cb = MFMA(Ax[mt][1].s, BH0l[1].s, cb);
                    cb = MFMA(Ah[mt][1].s, BH1h[1].s, cb);
                    cb = MFMA(Ah[mt][1].s, BH1l[1].s, cb);
                    g[mt] = ca + cb;
                }
            }
        }

        if (act) {
            u16* __restrict__ dhi = grp ? h1hi[cur] : h0hi[cur];
            u16* __restrict__ dlo = grp ? h1lo[cur] : h0lo[cur];
            #pragma unroll
            for (int mt = 0; mt < 4; ++mt) {
                f4 gg = g[mt];
                float si = sigm(gg[0]), sf = sigm(gg[1]);
                float tg = tanha(gg[2]), so = sigm(gg[3]);
                float cc = fmaf(sf, cst[mt], si * tg);
                cst[mt] = cc;
                float h = so * tanha(cc);
                if (grp && it - 1 == li) hlv[mt] = h;
                unsigned hb = __float_as_uint(h);
                float hhi = __uint_as_float(hb & 0xFFFF0000u);
                float hlo = h - hhi;
                int uu = ubase + 4 * mt;
                dhi[l15 * 72 + uu] = (u16)(hb >> 16);
                dlo[l15 * 72 + uu] = (u16)(unsigned)pkbf(hlo, hlo);
            }
        }

        WGBAR();   // lgkmcnt(0)+s_barrier; X prefetch stays in flight

        if (it < TT) {
            read_h2(h0hi[cur], h0lo[cur], hoff, BH0h, BH0l);
            if (grp) read_h2(h1hi[cur], h1lo[cur], hoff, BH1h, BH1l);
        }
    }

    // ---- head ----
    if (grp == 1) {
        #pragma unroll
        for (int mt = 0; mt < 4; ++mt)
            hlast[l15][ubase + 4 * mt] = hlv[mt];
    }
    __syncthreads();
    {
        int b = tid >> 5, o = tid & 31;
        float acc = fc1_b[o];
        const float* fw = fc1_w + o * 64;
        #pragma unroll
        for (int j = 0; j < 64; ++j)
            acc = fmaf(hlast[b][j], fw[j], acc);
        red[b * 32 + o] = fmaxf(acc, 0.f);
    }
    __syncthreads();
    if (tid < 32) {
        int b = tid >> 1, o = tid & 1;
        float acc = fc2_b[o];
        #pragma unroll
        for (int j = 0; j < 32; ++j)
            acc = fmaf(fc2_w[o * 32 + j], red[b * 32 + j], acc);
        out[(bb0 + b) * 2 + o] = acc;
    }
}

// ---------------------------------------------------------------------------
extern "C" void kernel_launch(void* const* d_in, const int* in_sizes, int n_in,
                              void* d_out, int out_size, void* d_ws, size_t ws_size,
                              hipStream_t stream)
{
    const float* conn  = (const float*)d_in[0];
    const int*   mask  = (const int*)  d_in[1];
    const float* w1_w  = (const float*)d_in[2];
    const float* w1_b  = (const float*)d_in[3];
    const float* w2_w  = (const float*)d_in[4];
    const float* w2_b  = (const float*)d_in[5];
    const float* Wih0  = (const float*)d_in[6];
    const float* Whh0  = (const float*)d_in[7];
    const float* bih0  = (const float*)d_in[8];
    const float* bhh0  = (const float*)d_in[9];
    const float* Wih1  = (const float*)d_in[10];
    const float* Whh1  = (const float*)d_in[11];
    const float* bih1  = (const float*)d_in[12];
    const float* bhh1  = (const float*)d_in[13];
    const float* fc1_w = (const float*)d_in[14];
    const float* fc1_b = (const float*)d_in[15];
    const float* fc2_w = (const float*)d_in[16];
    const float* fc2_b = (const float*)d_in[17];

    float* out = (float*)d_out;
    u16*   emb = (u16*)d_ws;          // 8.4 MB bf16

    const int num_graphs = BB * TT;

    encoder_mfma<<<8192, 64, 0, stream>>>(
        conn, mask, w1_w, w1_b, w2_w, w2_b, emb, num_graphs);

    lstm_mfma<<<16, 512, 0, stream>>>(
        emb, mask, Wih0, Whh0, bih0, bhh0, Wih1, Whh1, bih1, bhh1,
        fc1_w, fc1_b, fc2_w, fc2_b, out);
}

// Round 6
// 539.882 us; speedup vs baseline: 1.1435x; 1.0854x over previous
//
#include <hip/hip_runtime.h>
#include <hip/hip_bf16.h>
#include <math.h>

#define GN 19            // graph nodes
#define BB 256
#define TT 256

typedef short short8 __attribute__((ext_vector_type(8)));
typedef float f4 __attribute__((ext_vector_type(4)));
typedef unsigned short u16;

union Frag { int i[4]; short8 s; };

// wave-local LDS ordering fence: wait LDS ops, NO vmcnt drain, no barrier.
#define LWAIT() __asm__ volatile("s_waitcnt lgkmcnt(0)" ::: "memory")
// workgroup barrier WITHOUT vmcnt(0) drain: global loads stay in flight.
#define WGBAR() __asm__ volatile("s_waitcnt lgkmcnt(0)\ns_barrier" ::: "memory")
// opaque-register pin
#define PIN8(x) __asm__ volatile("" : "+v"(x))
#define PINF(x) __asm__ volatile("" : "+v"(x))

#define MFMA(a,b,c) __builtin_amdgcn_mfma_f32_16x16x32_bf16(a,b,c,0,0,0)

// packed RNE float pair -> bf16 pair (v_cvt_pk_bf16_f32 on gfx950)
__device__ __forceinline__ int pkbf(float a, float b) {
    __hip_bfloat162 h2 = __float22bfloat162_rn(make_float2(a, b));
    union { __hip_bfloat162 h; int i; } u; u.h = h2; return u.i;
}

__device__ __forceinline__ float fexp2(float x) { return __builtin_amdgcn_exp2f(x); }
__device__ __forceinline__ float frcp(float x)  { return __builtin_amdgcn_rcpf(x); }
__device__ __forceinline__ float sigm(float x)  { return frcp(1.f + fexp2(-1.4426950408889634f * x)); }
__device__ __forceinline__ float tanha(float x) { float e = fexp2(2.8853900817779268f * x); return 1.f - 2.f * frcp(e + 1.f); }

// ---------------------------------------------------------------------------
// Kernel A: graph encoder via bf16 MFMA (16x16x32).  UNCHANGED.
// ---------------------------------------------------------------------------
__global__ __launch_bounds__(64) void encoder_mfma(
    const float* __restrict__ conn,   // (G,19,19)
    const int*   __restrict__ mask,   // (G)
    const float* __restrict__ w1_w,   // (64,19)
    const float* __restrict__ w1_b,   // (64)
    const float* __restrict__ w2_w,   // (64,64)
    const float* __restrict__ w2_b,   // (64)
    u16* __restrict__ emb,            // (G,64) bf16
    int num_graphs)
{
    __shared__ float S[2304];         // 9216 B, reused 4 ways
    __shared__ float dis[32];
    __shared__ float ps[256];

    const int t = threadIdx.x;
    const int l15 = t & 15;
    const int quad = t >> 4;

    float km[8];
    #pragma unroll
    for (int j = 0; j < 8; ++j) km[j] = (quad * 8 + j < GN) ? 1.f : 0.f;

    int rr[6], cc[6];
    #pragma unroll
    for (int i = 0; i < 6; ++i) {
        int e = t + 64 * i;
        rr[i] = e / GN;
        cc[i] = e - rr[i] * GN;
    }

    Frag w1F[4];
    #pragma unroll
    for (int nt = 0; nt < 4; ++nt) {
        int n = nt * 16 + l15;
        #pragma unroll
        for (int p = 0; p < 4; ++p) {
            int k0 = quad * 8 + 2 * p, k1 = k0 + 1;
            float a = (k0 < GN) ? w1_w[n * GN + k0] : 0.f;
            float b = (k1 < GN) ? w1_w[n * GN + k1] : 0.f;
            w1F[nt].i[p] = pkbf(a, b);
        }
    }
    Frag w2F[2][4];
    #pragma unroll
    for (int kt = 0; kt < 2; ++kt)
        #pragma unroll
        for (int nt = 0; nt < 4; ++nt) {
            int n = nt * 16 + l15;
            #pragma unroll
            for (int p = 0; p < 4; ++p) {
                int k = kt * 32 + quad * 8 + 2 * p;
                w2F[kt][nt].i[p] = pkbf(w2_w[n * 64 + k], w2_w[n * 64 + k + 1]);
            }
        }
    float b1v[4], b2v[4];
    #pragma unroll
    for (int nt = 0; nt < 4; ++nt) {
        b1v[nt] = w1_b[nt * 16 + l15];
        b2v[nt] = w2_b[nt * 16 + l15];
    }

    float pf[6];
    {
        int g0 = blockIdx.x < num_graphs ? blockIdx.x : 0;
        const float* Ag = conn + (size_t)g0 * (GN * GN);
        #pragma unroll
        for (int i = 0; i < 6; ++i) {
            int e = t + 64 * i;
            if (e < GN * GN) pf[i] = Ag[e];
        }
    }

    #pragma unroll 1
    for (int g = blockIdx.x; g < num_graphs; g += gridDim.x) {
        #pragma unroll
        for (int i = 0; i < 4; ++i) {
            int s = t + 64 * i;
            int row = s >> 3, c4 = s & 7;
            f4 z = {0.f, 0.f, 0.f, 0.f};
            *(f4*)&S[row * 68 + c4 * 4] = z;
        }
        LWAIT();
        #pragma unroll
        for (int i = 0; i < 6; ++i) {
            if (t + 64 * i < GN * GN) S[rr[i] * 68 + cc[i]] = pf[i];
        }
        {
            int gn = g + gridDim.x;
            const float* Ag = conn + (size_t)(gn < num_graphs ? gn : g) * (GN * GN);
            #pragma unroll
            for (int i = 0; i < 6; ++i) {
                int e = t + 64 * i;
                if (e < GN * GN) pf[i] = Ag[e];
            }
        }
        LWAIT();

        if (t < 32) {
            float dv = 0.f;
            if (t < GN) {
                float d = 1.0f;
                #pragma unroll
                for (int c4 = 0; c4 < 8; ++c4) {
                    f4 v = *(f4*)&S[t * 68 + c4 * 4];
                    d += v.x + v.y + v.z + v.w;
                }
                dv = rsqrtf(d);
            }
            dis[t] = dv;
        }
        LWAIT();

        float dk[8];
        {
            f4 v0 = *(f4*)&dis[quad * 8];
            f4 v1 = *(f4*)&dis[quad * 8 + 4];
            dk[0]=v0.x; dk[1]=v0.y; dk[2]=v0.z; dk[3]=v0.w;
            dk[4]=v1.x; dk[5]=v1.y; dk[6]=v1.z; dk[7]=v1.w;
        }
        Frag aF[2], anF[2];
        #pragma unroll
        for (int mt = 0; mt < 2; ++mt) {
            int m = l15 + 16 * mt;
            float dm = dis[m];
            f4 v0 = *(f4*)&S[m * 68 + quad * 8];
            f4 v1 = *(f4*)&S[m * 68 + quad * 8 + 4];
            float av[8] = {v0.x, v0.y, v0.z, v0.w, v1.x, v1.y, v1.z, v1.w};
            float an[8];
            #pragma unroll
            for (int j = 0; j < 8; ++j) {
                int k = quad * 8 + j;
                an[j] = (av[j] + (m == k ? 1.f : 0.f)) * dm * dk[j];
            }
            #pragma unroll
            for (int p = 0; p < 4; ++p) {
                aF[mt].i[p]  = pkbf(av[2*p], av[2*p+1]);
                anF[mt].i[p] = pkbf(an[2*p], an[2*p+1]);
            }
        }
        LWAIT();

        #pragma unroll
        for (int mt = 0; mt < 2; ++mt)
            #pragma unroll
            for (int nt = 0; nt < 4; ++nt) {
                float bb = b1v[nt];
                f4 c = {bb, bb, bb, bb};
                c = MFMA(aF[mt].s, w1F[nt].s, c);
                int col = nt * 16 + l15;
                #pragma unroll
                for (int r = 0; r < 4; ++r)
                    S[col * 36 + (mt * 16 + quad * 4 + r)] = c[r];
            }
        LWAIT();

        Frag hF[4];
        #pragma unroll
        for (int nt = 0; nt < 4; ++nt) {
            int n = nt * 16 + l15;
            f4 v0 = *(f4*)&S[n * 36 + quad * 8];
            f4 v1 = *(f4*)&S[n * 36 + quad * 8 + 4];
            float vv[8] = {v0.x, v0.y, v0.z, v0.w, v1.x, v1.y, v1.z, v1.w};
            #pragma unroll
            for (int p = 0; p < 4; ++p)
                hF[nt].i[p] = pkbf(vv[2*p] * km[2*p], vv[2*p+1] * km[2*p+1]);
        }
        LWAIT();

        #pragma unroll
        for (int mt = 0; mt < 2; ++mt)
            #pragma unroll
            for (int nt = 0; nt < 4; ++nt) {
                f4 c = {0.f, 0.f, 0.f, 0.f};
                c = MFMA(anF[mt].s, hF[nt].s, c);
                int col = nt * 16 + l15;
                #pragma unroll
                for (int r = 0; r < 4; ++r)
                    S[(mt * 16 + quad * 4 + r) * 68 + col] = fmaxf(c[r], 0.f);
            }
        LWAIT();

        Frag xF[2][2];
        #pragma unroll
        for (int mt = 0; mt < 2; ++mt) {
            int m = l15 + 16 * mt;
            #pragma unroll
            for (int kt = 0; kt < 2; ++kt) {
                f4 v0 = *(f4*)&S[m * 68 + kt * 32 + quad * 8];
                f4 v1 = *(f4*)&S[m * 68 + kt * 32 + quad * 8 + 4];
                xF[mt][kt].i[0] = pkbf(v0.x, v0.y);
                xF[mt][kt].i[1] = pkbf(v0.z, v0.w);
                xF[mt][kt].i[2] = pkbf(v1.x, v1.y);
                xF[mt][kt].i[3] = pkbf(v1.z, v1.w);
            }
        }
        LWAIT();

        #pragma unroll
        for (int mt = 0; mt < 2; ++mt)
            #pragma unroll
            for (int nt = 0; nt < 4; ++nt) {
                float bb = b2v[nt];
                f4 c = {bb, bb, bb, bb};
                c = MFMA(xF[mt][0].s, w2F[0][nt].s, c);
                c = MFMA(xF[mt][1].s, w2F[1][nt].s, c);
                int col = nt * 16 + l15;
                #pragma unroll
                for (int r = 0; r < 4; ++r)
                    S[col * 36 + (mt * 16 + quad * 4 + r)] = c[r];
            }
        LWAIT();

        Frag hG[4];
        #pragma unroll
        for (int nt = 0; nt < 4; ++nt) {
            int n = nt * 16 + l15;
            f4 v0 = *(f4*)&S[n * 36 + quad * 8];
            f4 v1 = *(f4*)&S[n * 36 + quad * 8 + 4];
            float vv[8] = {v0.x, v0.y, v0.z, v0.w, v1.x, v1.y, v1.z, v1.w};
            #pragma unroll
            for (int p = 0; p < 4; ++p)
                hG[nt].i[p] = pkbf(vv[2*p] * km[2*p], vv[2*p+1] * km[2*p+1]);
        }

        float cs[4];
        #pragma unroll
        for (int nt = 0; nt < 4; ++nt) cs[nt] = 0.f;
        #pragma unroll
        for (int mt = 0; mt < 2; ++mt)
            #pragma unroll
            for (int nt = 0; nt < 4; ++nt) {
                f4 c = {0.f, 0.f, 0.f, 0.f};
                c = MFMA(anF[mt].s, hG[nt].s, c);
                if (mt == 0) {
                    cs[nt] += fmaxf(c[0], 0.f) + fmaxf(c[1], 0.f)
                            + fmaxf(c[2], 0.f) + fmaxf(c[3], 0.f);
                } else if (quad == 0) {
                    cs[nt] += fmaxf(c[0], 0.f) + fmaxf(c[1], 0.f) + fmaxf(c[2], 0.f);
                }
            }
        #pragma unroll
        for (int nt = 0; nt < 4; ++nt)
            ps[quad * 64 + nt * 16 + l15] = cs[nt];
        LWAIT();
        float tot = ps[t] + ps[64 + t] + ps[128 + t] + ps[192 + t];
        float mf = (float)mask[g];
        float v = tot * (1.f / 19.f) * mf;
        emb[(size_t)g * 64 + t] = (u16)(unsigned)pkbf(v, v);  // low16 = bf16RNE(v)
        LWAIT();
    }
}

// read single-bf16 h B-fragments straight from LDS (zero VALU)
__device__ __forceinline__ void read_h1(const u16* __restrict__ hs,
                                        int off, Frag* __restrict__ BH)
{
    #pragma unroll
    for (int kt = 0; kt < 2; ++kt) {
        int4 vh = *(const int4*)&hs[off + kt * 32];
        BH[kt].i[0] = vh.x; BH[kt].i[1] = vh.y;
        BH[kt].i[2] = vh.z; BH[kt].i[3] = vh.w;
    }
}

// ---------------------------------------------------------------------------
// Kernel B v6: both LSTM layers + head via MFMA, layer-split waves, SINGLE
// bf16 h.  R3->R4 falsified the width theories (halving waves/LDS/conflicts
// changed nothing; per-active-CU: VALU ~14%/SIMD, MFMA ~8%/SIMD, ~75% idle)
// -> the step is a serial chain: read h -> MFMA chain -> act -> write ->
// barrier.  This round SHORTENS the chain: h carried as single bf16 (the
// hi/lo f32-equivalent pair is dropped):
//   - dependent-MFMA chain depth after h-read: 3-4 -> 2
//   - MFMA/step: L0 24->16, L1 32->16
//   - h-exchange LDS reads: 96 -> 24 b128/CU-step; writes halve
//   - act tail loses the hi/lo split (and/sub/perm gone)
// Numerics: absmax has been encoder-dominated (bit-identical 0.00098 since
// the f32 LSTM); bf16-h adds ~2^-9 relative through contractive gates ->
// predicted absmax 1-4e-3.  Acknowledged risk; revert if check fails.
// ---------------------------------------------------------------------------
__global__ __launch_bounds__(512) __attribute__((amdgpu_waves_per_eu(2, 2)))
void lstm_mfma(
    const u16*   __restrict__ x,      // (B*T, 64) bf16 = emb
    const int*   __restrict__ mask,   // (B, T)
    const float* __restrict__ Wih0, const float* __restrict__ Whh0,
    const float* __restrict__ bih0, const float* __restrict__ bhh0,
    const float* __restrict__ Wih1, const float* __restrict__ Whh1,
    const float* __restrict__ bih1, const float* __restrict__ bhh1,
    const float* __restrict__ fc1_w, const float* __restrict__ fc1_b,
    const float* __restrict__ fc2_w, const float* __restrict__ fc2_b,
    float* __restrict__ out)          // (B, 2)
{
    __shared__ __attribute__((aligned(16))) u16 h0s[2][16 * 72];
    __shared__ __attribute__((aligned(16))) u16 h1s[2][16 * 72];
    __shared__ float hlast[16][68];
    __shared__ float red[512];
    __shared__ int   li_s[16];

    const int tid  = threadIdx.x;     // 0..511
    const int w    = tid >> 6;        // wave 0..7
    const int grp  = w >> 2;          // 0: layer 0 (waves 0-3), 1: layer 1
    const int wl   = w & 3;           // wave within layer
    const int lane = tid & 63;
    const int l15  = lane & 15;       // batch col
    const int quad = lane >> 4;
    const int bb0  = blockIdx.x * 16;

    // zero h1 dbuf[0] (read as h1(-1)=0 after it=0's barrier)
    for (int i = tid; i < 16 * 72; i += 512) h1s[0][i] = 0;

    // ---- lastidx per batch row ----
    {
        int b16 = tid >> 5, j = tid & 31;
        int s = 0;
        #pragma unroll
        for (int c8 = 0; c8 < 8; ++c8)
            s += mask[(bb0 + b16) * TT + j + 32 * c8];
        red[tid] = (float)s;
    }
    __syncthreads();
    if (tid < 16) {
        float s = 0.f;
        #pragma unroll
        for (int j = 0; j < 32; ++j) s += red[tid * 32 + j];
        int li = (int)s - 1;
        li_s[tid] = li < 0 ? 0 : (li > TT - 1 ? TT - 1 : li);
    }
    __syncthreads();
    const int li = li_s[l15];

    // ---- this wave's layer weights: 4 gate-tiles, 16 frags ----
    // tile-row r of tile mg maps to orig gate row (r&3)*64 + (mg*4+(r>>2));
    // C-frag lane (l15=batch, quad): rows quad*4+r = gates r of unit mg*4+quad.
    const float* __restrict__ Wx = grp ? Wih1 : Wih0;
    const float* __restrict__ Wh = grp ? Whh1 : Whh0;
    const float* __restrict__ bi = grp ? bih1 : bih0;
    const float* __restrict__ bh = grp ? bhh1 : bhh0;

    Frag Ax[4][2], Ah[4][2];
    f4 biasv[4];
    #pragma unroll
    for (int mt = 0; mt < 4; ++mt) {
        int mg = 4 * wl + mt;
        int orig = (l15 & 3) * 64 + (mg * 4 + (l15 >> 2));
        #pragma unroll
        for (int kt = 0; kt < 2; ++kt)
            #pragma unroll
            for (int p = 0; p < 4; ++p) {
                int k = kt * 32 + quad * 8 + 2 * p;
                Ax[mt][kt].i[p] = pkbf(Wx[orig * 64 + k], Wx[orig * 64 + k + 1]);
                Ah[mt][kt].i[p] = pkbf(Wh[orig * 64 + k], Wh[orig * 64 + k + 1]);
            }
        int uu = mg * 4 + quad;
        #pragma unroll
        for (int r = 0; r < 4; ++r)
            biasv[mt][r] = bi[r * 64 + uu] + bh[r * 64 + uu];
    }
    #pragma unroll
    for (int mt = 0; mt < 4; ++mt) {
        PIN8(Ax[mt][0].s); PIN8(Ax[mt][1].s);
        PIN8(Ah[mt][0].s); PIN8(Ah[mt][1].s);
        PINF(biasv[mt]);
    }

    // unit owned by (mt, quad): 16*wl + 4*mt + quad
    const int ubase = 16 * wl + quad;
    const int hoff = l15 * 72 + quad * 8;   // B-frag read base

    // ---- state ----
    Frag BH0[2], BH1[2], BXn[2];
    #pragma unroll
    for (int kt = 0; kt < 2; ++kt)
        #pragma unroll
        for (int p = 0; p < 4; ++p) {
            BXn[kt].i[p] = 0; BH0[kt].i[p] = 0; BH1[kt].i[p] = 0;
        }
    float cst[4] = {0.f, 0.f, 0.f, 0.f};
    float hlv[4] = {0.f, 0.f, 0.f, 0.f};

    const u16* __restrict__ xb = x + (size_t)(bb0 + l15) * TT * 64;
    if (grp == 0) {
        BXn[0] = *(const Frag*)&xb[quad * 8];
        BXn[1] = *(const Frag*)&xb[32 + quad * 8];
    }

    // iteration it: layer 0 does step it; layer 1 does step it-1.
    #pragma unroll 1
    for (int it = 0; it <= TT; ++it) {
        const int cur = it & 1;
        f4 g[4];
        bool act = false;

        if (grp == 0) {
            if (it < TT) {
                act = true;
                Frag bx0 = BXn[0], bx1 = BXn[1];
                int tn = it + 1 < TT ? it + 1 : TT - 1;
                BXn[0] = *(const Frag*)&xb[(size_t)tn * 64 + quad * 8];
                BXn[1] = *(const Frag*)&xb[(size_t)tn * 64 + 32 + quad * 8];

                #pragma unroll
                for (int mt = 0; mt < 4; ++mt) {
                    // two chains of depth 2; x-MFMA first (independent of h)
                    f4 ca = biasv[mt];
                    ca = MFMA(Ax[mt][0].s, bx0.s,    ca);
                    ca = MFMA(Ah[mt][0].s, BH0[0].s, ca);
                    f4 cb = {0.f, 0.f, 0.f, 0.f};
                    cb = MFMA(Ax[mt][1].s, bx1.s,    cb);
                    cb = MFMA(Ah[mt][1].s, BH0[1].s, cb);
                    g[mt] = ca + cb;
                }
            }
        } else {
            if (it >= 1) {
                act = true;
                #pragma unroll
                for (int mt = 0; mt < 4; ++mt) {
                    f4 ca = biasv[mt];
                    ca = MFMA(Ax[mt][0].s, BH0[0].s, ca);
                    ca = MFMA(Ah[mt][0].s, BH1[0].s, ca);
                    f4 cb = {0.f, 0.f, 0.f, 0.f};
                    cb = MFMA(Ax[mt][1].s, BH0[1].s, cb);
                    cb = MFMA(Ah[mt][1].s, BH1[1].s, cb);
                    g[mt] = ca + cb;
                }
            }
        }

        if (act) {
            u16* __restrict__ dst = grp ? h1s[cur] : h0s[cur];
            #pragma unroll
            for (int mt = 0; mt < 4; ++mt) {
                f4 gg = g[mt];
                float si = sigm(gg[0]), sf = sigm(gg[1]);
                float tg = tanha(gg[2]), so = sigm(gg[3]);
                float cc = fmaf(sf, cst[mt], si * tg);
                cst[mt] = cc;
                float h = so * tanha(cc);
                if (grp && it - 1 == li) hlv[mt] = h;
                dst[l15 * 72 + ubase + 4 * mt] = (u16)(unsigned)pkbf(h, h);
            }
        }

        WGBAR();   // lgkmcnt(0)+s_barrier; X prefetch stays in flight

        if (it < TT) {
            read_h1(h0s[cur], hoff, BH0);
            if (grp) read_h1(h1s[cur], hoff, BH1);
        }
    }

    // ---- head ----
    if (grp == 1) {
        #pragma unroll
        for (int mt = 0; mt < 4; ++mt)
            hlast[l15][ubase + 4 * mt] = hlv[mt];
    }
    __syncthreads();
    {
        int b = tid >> 5, o = tid & 31;
        float acc = fc1_b[o];
        const float* fw = fc1_w + o * 64;
        #pragma unroll
        for (int j = 0; j < 64; ++j)
            acc = fmaf(hlast[b][j], fw[j], acc);
        red[b * 32 + o] = fmaxf(acc, 0.f);
    }
    __syncthreads();
    if (tid < 32) {
        int b = tid >> 1, o = tid & 1;
        float acc = fc2_b[o];
        #pragma unroll
        for (int j = 0; j < 32; ++j)
            acc = fmaf(fc2_w[o * 32 + j], red[b * 32 + j], acc);
        out[(bb0 + b) * 2 + o] = acc;
    }
}

// ---------------------------------------------------------------------------
extern "C" void kernel_launch(void* const* d_in, const int* in_sizes, int n_in,
                              void* d_out, int out_size, void* d_ws, size_t ws_size,
                              hipStream_t stream)
{
    const float* conn  = (const float*)d_in[0];
    const int*   mask  = (const int*)  d_in[1];
    const float* w1_w  = (const float*)d_in[2];
    const float* w1_b  = (const float*)d_in[3];
    const float* w2_w  = (const float*)d_in[4];
    const float* w2_b  = (const float*)d_in[5];
    const float* Wih0  = (const float*)d_in[6];
    const float* Whh0  = (const float*)d_in[7];
    const float* bih0  = (const float*)d_in[8];
    const float* bhh0  = (const float*)d_in[9];
    const float* Wih1  = (const float*)d_in[10];
    const float* Whh1  = (const float*)d_in[11];
    const float* bih1  = (const float*)d_in[12];
    const float* bhh1  = (const float*)d_in[13];
    const float* fc1_w = (const float*)d_in[14];
    const float* fc1_b = (const float*)d_in[15];
    const float* fc2_w = (const float*)d_in[16];
    const float* fc2_b = (const float*)d_in[17];

    float* out = (float*)d_out;
    u16*   emb = (u16*)d_ws;          // 8.4 MB bf16

    const int num_graphs = BB * TT;

    encoder_mfma<<<8192, 64, 0, stream>>>(
        conn, mask, w1_w, w1_b, w2_w, w2_b, emb, num_graphs);

    lstm_mfma<<<16, 512, 0, stream>>>(
        emb, mask, Wih0, Whh0, bih0, bhh0, Wih1, Whh1, bih1, bhh1,
        fc1_w, fc1_b, fc2_w, fc2_b, out);
}